// Round 4
// baseline (4848.355 us; speedup 1.0000x reference)
//
#include <hip/hip_runtime.h>
#include <hip/hip_bf16.h>

// Hierarchical attention: 3 levels of (QKV -> 4-head MHA -> out-proj -> masked mean pool).
// fp32 end-to-end (no fp32 MFMA on CDNA4; precision threshold is tight).
//
// Level 1 (word): 2048 sequences, L=64  -> sent [2048,256]   (word_kernel, register-tiled)
// Level 2 (sent):  128 sequences, L=16  -> sect [128,256]    (pool_kernel<16>)
// Level 3 (sect):   16 sequences, L=8   -> doc  [16,256]     (pool_kernel<8>)

#define HS 68   // head-tile LDS stride (64 + 4 pad), 272B = 16B-aligned

__global__ __launch_bounds__(256) void word_kernel(
    const float* __restrict__ x,      // [NSEQ][64][256]
    const int*   __restrict__ am,     // [NSEQ][64]
    const float* __restrict__ Wqkv,   // [768][256]
    const float* __restrict__ bqkv,   // [768]
    const float* __restrict__ Wo,     // [256][256]
    const float* __restrict__ bo,     // [256]
    float* __restrict__ outp,         // [NSEQ][256]
    float* __restrict__ smask)        // [NSEQ]
{
    __shared__ __align__(16) float Qh[64 * HS];   // Q tile, later attn
    __shared__ __align__(16) float Kh[64 * HS];   // K tile, later O tile
    __shared__ __align__(16) float Vh[64 * HS];   // V tile
    __shared__ float msk[64];
    __shared__ float smsum;

    const int t  = threadIdx.x;
    const int tx = t & 15;          // 16 col-groups
    const int ty = t >> 4;          // 16 row-groups (4 rows each)
    const int b  = blockIdx.x;
    const float* xb = x + (size_t)b * (64 * 256);

    if (t < 64) msk[t] = (float)am[b * 64 + t];
    __syncthreads();
    if (t == 0) { float s = 0.f; for (int i = 0; i < 64; ++i) s += msk[i]; smsum = s; }

    // out-proj accumulator: rows i = ty*4+a, cols j = q*16+tx
    float outacc[4][16];
    #pragma unroll
    for (int a = 0; a < 4; ++a) {
        #pragma unroll
        for (int q = 0; q < 16; ++q) outacc[a][q] = 0.f;
    }

    for (int h = 0; h < 4; ++h) {
        __syncthreads();  // previous head's consumers of Qh/Kh/Vh are done

        // ---- QKV projection for this head: dst[i][d] = sum_c x[i][c]*W[col][c] + b  ----
        for (int m = 0; m < 3; ++m) {
            float acc[4][4] = {};
            const float* Wbase = Wqkv + (size_t)(m * 256 + h * 64) * 256;
            for (int c = 0; c < 256; c += 4) {
                float4 xv[4];
                #pragma unroll
                for (int a = 0; a < 4; ++a)
                    xv[a] = *(const float4*)(xb + (ty * 4 + a) * 256 + c);
                #pragma unroll
                for (int bb = 0; bb < 4; ++bb) {
                    float4 wv = *(const float4*)(Wbase + (size_t)(bb * 16 + tx) * 256 + c);
                    #pragma unroll
                    for (int a = 0; a < 4; ++a)
                        acc[a][bb] += xv[a].x * wv.x + xv[a].y * wv.y
                                    + xv[a].z * wv.z + xv[a].w * wv.w;
                }
            }
            float* dst = (m == 0) ? Qh : ((m == 1) ? Kh : Vh);
            const float* bias = bqkv + m * 256 + h * 64;
            #pragma unroll
            for (int bb = 0; bb < 4; ++bb) {
                float bv = bias[bb * 16 + tx];
                #pragma unroll
                for (int a = 0; a < 4; ++a)
                    dst[(ty * 4 + a) * HS + bb * 16 + tx] = acc[a][bb] + bv;
            }
        }
        __syncthreads();

        // ---- scores: sacc[a][bb] = (q_i . k_j)/8 + maskterm,  i=ty*4+a, j=bb*16+tx ----
        float sacc[4][4] = {};
        for (int d = 0; d < 64; d += 4) {
            float4 q4[4], k4[4];
            #pragma unroll
            for (int a = 0; a < 4; ++a)
                q4[a] = *(const float4*)&Qh[(ty * 4 + a) * HS + d];
            #pragma unroll
            for (int bb = 0; bb < 4; ++bb)
                k4[bb] = *(const float4*)&Kh[(bb * 16 + tx) * HS + d];
            #pragma unroll
            for (int a = 0; a < 4; ++a) {
                #pragma unroll
                for (int bb = 0; bb < 4; ++bb)
                    sacc[a][bb] += q4[a].x * k4[bb].x + q4[a].y * k4[bb].y
                                 + q4[a].z * k4[bb].z + q4[a].w * k4[bb].w;
            }
        }
        float mterm[4];
        #pragma unroll
        for (int bb = 0; bb < 4; ++bb) mterm[bb] = (1.0f - msk[bb * 16 + tx]) * -1e9f;
        #pragma unroll
        for (int a = 0; a < 4; ++a) {
            #pragma unroll
            for (int bb = 0; bb < 4; ++bb)
                sacc[a][bb] = sacc[a][bb] * 0.125f + mterm[bb];
        }

        // ---- softmax over j (row spread across 16 lanes, 4 cols each) ----
        float rm[4], rs[4];
        #pragma unroll
        for (int a = 0; a < 4; ++a)
            rm[a] = fmaxf(fmaxf(sacc[a][0], sacc[a][1]), fmaxf(sacc[a][2], sacc[a][3]));
        #pragma unroll
        for (int off = 1; off < 16; off <<= 1) {
            #pragma unroll
            for (int a = 0; a < 4; ++a)
                rm[a] = fmaxf(rm[a], __shfl_xor(rm[a], off, 16));
        }
        #pragma unroll
        for (int a = 0; a < 4; ++a) {
            float s = 0.f;
            #pragma unroll
            for (int bb = 0; bb < 4; ++bb) {
                float e = expf(sacc[a][bb] - rm[a]);
                sacc[a][bb] = e; s += e;
            }
            rs[a] = s;
        }
        #pragma unroll
        for (int off = 1; off < 16; off <<= 1) {
            #pragma unroll
            for (int a = 0; a < 4; ++a)
                rs[a] += __shfl_xor(rs[a], off, 16);
        }
        #pragma unroll
        for (int a = 0; a < 4; ++a) {
            float inv = 1.0f / rs[a];
            #pragma unroll
            for (int bb = 0; bb < 4; ++bb) sacc[a][bb] *= inv;
        }
        __syncthreads();  // everyone done reading Qh/Kh
        #pragma unroll
        for (int a = 0; a < 4; ++a) {
            #pragma unroll
            for (int bb = 0; bb < 4; ++bb)
                Qh[(ty * 4 + a) * HS + bb * 16 + tx] = sacc[a][bb];  // attn
        }
        __syncthreads();

        // ---- O = attn @ V : oacc[a][bb], d = bb*16+tx ----
        float oacc[4][4] = {};
        for (int j = 0; j < 64; j += 4) {
            float av[4][4];
            #pragma unroll
            for (int a = 0; a < 4; ++a) {
                float4 t4 = *(const float4*)&Qh[(ty * 4 + a) * HS + j];
                av[a][0] = t4.x; av[a][1] = t4.y; av[a][2] = t4.z; av[a][3] = t4.w;
            }
            #pragma unroll
            for (int u = 0; u < 4; ++u) {
                float vv[4];
                #pragma unroll
                for (int bb = 0; bb < 4; ++bb) vv[bb] = Vh[(j + u) * HS + bb * 16 + tx];
                #pragma unroll
                for (int a = 0; a < 4; ++a) {
                    #pragma unroll
                    for (int bb = 0; bb < 4; ++bb)
                        oacc[a][bb] += av[a][u] * vv[bb];
                }
            }
        }
        __syncthreads();  // AV reads done, safe to overwrite Kh with O
        #pragma unroll
        for (int a = 0; a < 4; ++a) {
            #pragma unroll
            for (int bb = 0; bb < 4; ++bb)
                Kh[(ty * 4 + a) * HS + bb * 16 + tx] = oacc[a][bb];
        }
        __syncthreads();

        // ---- out-proj partial: outacc[a][q] += sum_d O[i][d] * Wo[j][h*64+d] ----
        for (int d = 0; d < 64; d += 4) {
            float o4[4][4];
            #pragma unroll
            for (int a = 0; a < 4; ++a) {
                float4 t4 = *(const float4*)&Kh[(ty * 4 + a) * HS + d];
                o4[a][0] = t4.x; o4[a][1] = t4.y; o4[a][2] = t4.z; o4[a][3] = t4.w;
            }
            #pragma unroll
            for (int q = 0; q < 16; ++q) {
                float4 wv = *(const float4*)(Wo + (size_t)(q * 16 + tx) * 256 + h * 64 + d);
                #pragma unroll
                for (int a = 0; a < 4; ++a)
                    outacc[a][q] += o4[a][0] * wv.x + o4[a][1] * wv.y
                                  + o4[a][2] * wv.z + o4[a][3] * wv.w;
            }
        }
    } // heads

    // ---- masked mean pool over rows ----
    float part[16];
    #pragma unroll
    for (int q = 0; q < 16; ++q) {
        float s = 0.f;
        #pragma unroll
        for (int a = 0; a < 4; ++a) s += outacc[a][q] * msk[ty * 4 + a];
        part[q] = s;
    }
    __syncthreads();  // safe: Qh last read before a barrier
    #pragma unroll
    for (int q = 0; q < 16; ++q) Qh[ty * 257 + q * 16 + tx] = part[q];
    __syncthreads();
    {
        float s = 0.f;
        #pragma unroll
        for (int g = 0; g < 16; ++g) s += Qh[g * 257 + t];
        float msum = smsum;
        outp[(size_t)b * 256 + t] = (s + bo[t] * msum) / (msum + 1e-10f);
    }
    if (t == 0) smask[b] = (smsum > 0.f) ? 1.f : 0.f;
}

// Generic small-L level (L=16 sent, L=8 sect). Tiny workloads; simple structure.
template <int L>
__global__ __launch_bounds__(256) void pool_kernel(
    const float* __restrict__ xin,  // [N][L][256]
    const float* __restrict__ mk,   // [N][L] float 0/1
    const float* __restrict__ Wqkv, const float* __restrict__ bqkv,
    const float* __restrict__ Wo,   const float* __restrict__ bo,
    float* __restrict__ outp,       // [N][256]
    float* __restrict__ outmask)    // [N] or nullptr
{
    __shared__ __align__(16) float Xs[L * 260];
    __shared__ __align__(16) float QKV[L * 772];
    __shared__ float At[4 * L * (L + 1)];
    __shared__ __align__(16) float Oh[L * 260];
    __shared__ float msk[L];
    __shared__ float smsum;

    const int t = threadIdx.x, b = blockIdx.x;
    const float* xb = xin + (size_t)b * L * 256;

    for (int idx = t; idx < L * 256; idx += 256)
        Xs[(idx >> 8) * 260 + (idx & 255)] = xb[idx];
    if (t < L) msk[t] = mk[b * L + t];
    __syncthreads();
    if (t == 0) { float s = 0.f; for (int i = 0; i < L; ++i) s += msk[i]; smsum = s; }

    // QKV: L*768 outputs, 256-length dots
    for (int idx = t; idx < L * 768; idx += 256) {
        int l = idx / 768, col = idx - l * 768;
        const float* xr = Xs + l * 260;
        const float* wr = Wqkv + (size_t)col * 256;
        float s = bqkv[col];
        for (int c = 0; c < 256; c += 4) {
            float4 xv = *(const float4*)(xr + c);
            float4 wv = *(const float4*)(wr + c);
            s += xv.x * wv.x + xv.y * wv.y + xv.z * wv.z + xv.w * wv.w;
        }
        QKV[l * 772 + col] = s;
    }
    __syncthreads();

    // scores + softmax: one (head,row) per thread
    if (t < 4 * L) {
        int h = t / L, i = t - h * L;
        float sc[L];
        float m = -3.4e38f;
        #pragma unroll
        for (int j = 0; j < L; ++j) {
            const float* qr = QKV + i * 772 + h * 64;
            const float* kr = QKV + j * 772 + 256 + h * 64;
            float s = 0.f;
            for (int d = 0; d < 64; d += 4) {
                float4 qv = *(const float4*)(qr + d);
                float4 kv = *(const float4*)(kr + d);
                s += qv.x * kv.x + qv.y * kv.y + qv.z * kv.z + qv.w * kv.w;
            }
            s = s * 0.125f + (1.0f - msk[j]) * (-1e9f);
            sc[j] = s; m = fmaxf(m, s);
        }
        float sum = 0.f;
        #pragma unroll
        for (int j = 0; j < L; ++j) { float e = expf(sc[j] - m); sc[j] = e; sum += e; }
        float inv = 1.0f / sum;
        #pragma unroll
        for (int j = 0; j < L; ++j) At[(h * L + i) * (L + 1) + j] = sc[j] * inv;
    }
    __syncthreads();

    // O = attn @ V
    for (int idx = t; idx < L * 256; idx += 256) {
        int l = idx >> 8, d8 = idx & 255;
        int h = d8 >> 6, d = d8 & 63;
        float s = 0.f;
        #pragma unroll
        for (int j = 0; j < L; ++j)
            s += At[(h * L + l) * (L + 1) + j] * QKV[j * 772 + 512 + h * 64 + d];
        Oh[l * 260 + d8] = s;
    }
    __syncthreads();

    // out-proj + masked pool: one output column per thread
    {
        int j = t;
        const float* wr = Wo + (size_t)j * 256;
        float bj = bo[j];
        float accp = 0.f;
        for (int l = 0; l < L; ++l) {
            const float* orow = Oh + l * 260;
            float s = 0.f;
            for (int c = 0; c < 256; c += 4) {
                float4 ov = *(const float4*)(orow + c);
                float4 wv = *(const float4*)(wr + c);
                s += ov.x * wv.x + ov.y * wv.y + ov.z * wv.z + ov.w * wv.w;
            }
            accp += (s + bj) * msk[l];
        }
        float msum = smsum;
        outp[(size_t)b * 256 + j] = accp / (msum + 1e-10f);
    }
    if (outmask && t == 0) outmask[b] = (smsum > 0.f) ? 1.f : 0.f;
}

extern "C" void kernel_launch(void* const* d_in, const int* in_sizes, int n_in,
                              void* d_out, int out_size, void* d_ws, size_t ws_size,
                              hipStream_t stream) {
    (void)in_sizes; (void)n_in; (void)out_size; (void)ws_size;
    const float* we  = (const float*)d_in[0];
    const int*   am  = (const int*)d_in[1];
    const float* wW  = (const float*)d_in[2];
    const float* wb  = (const float*)d_in[3];
    const float* wO  = (const float*)d_in[4];
    const float* wob = (const float*)d_in[5];
    const float* sW  = (const float*)d_in[6];
    const float* sb  = (const float*)d_in[7];
    const float* sO  = (const float*)d_in[8];
    const float* sob = (const float*)d_in[9];
    const float* cW  = (const float*)d_in[10];
    const float* cb  = (const float*)d_in[11];
    const float* cO  = (const float*)d_in[12];
    const float* cob = (const float*)d_in[13];

    float* ws     = (float*)d_ws;
    float* sentb  = ws;                   // 2048*256
    float* sectb  = sentb + 2048 * 256;   // 128*256
    float* smaskb = sectb + 128 * 256;    // 2048
    float* cmaskb = smaskb + 2048;        // 128

    word_kernel<<<2048, 256, 0, stream>>>(we, am, wW, wb, wO, wob, sentb, smaskb);
    pool_kernel<16><<<128, 256, 0, stream>>>(sentb, smaskb, sW, sb, sO, sob, sectb, cmaskb);
    pool_kernel<8><<<16, 256, 0, stream>>>(sectb, cmaskb, cW, cb, cO, cob, (float*)d_out, nullptr);
}

// Round 5
// 1630.620 us; speedup vs baseline: 2.9733x; 2.9733x over previous
//
#include <hip/hip_runtime.h>
#include <hip/hip_bf16.h>

// Hierarchical attention, 3 levels. Level 1 (word, 2048 seq x L=64) rewritten
// with split-bf16 (hi/lo) MFMA: every GEMM = 3x mfma_f32_16x16x32_bf16
// (hi*hi + hi*lo + lo*hi), giving ~fp32 precision at matrix-core rate.
// Values stored packed: u32 = (bf16_hi << 16) | bf16_lo.
// Levels 2/3 (tiny) stay fp32 vector (pool_kernel).

typedef short bf16x8 __attribute__((ext_vector_type(8)));   // 8 bf16 (4 VGPRs)
typedef float f32x4 __attribute__((ext_vector_type(4)));
typedef unsigned int u32x4 __attribute__((ext_vector_type(4)));

__device__ __forceinline__ unsigned int pack_hl(float f) {
    unsigned int u = __builtin_bit_cast(unsigned int, f);
    unsigned int h = (u + 0x7FFFu + ((u >> 16) & 1u)) >> 16;      // RNE bf16(f)
    float hf = __builtin_bit_cast(float, h << 16);
    unsigned int v = __builtin_bit_cast(unsigned int, f - hf);
    unsigned int lo = (v + 0x7FFFu + ((v >> 16) & 1u)) >> 16;     // RNE bf16(f-hi)
    return (h << 16) | (lo & 0xFFFFu);
}

// 8 packed u32 (elems k..k+7) -> hi-fragment (4 u32 = 8 bf16) + lo-fragment
__device__ __forceinline__ void unpack8(u32x4 a, u32x4 b, u32x4& hi, u32x4& lo) {
    hi[0] = __builtin_amdgcn_perm(a[1], a[0], 0x07060302u);
    hi[1] = __builtin_amdgcn_perm(a[3], a[2], 0x07060302u);
    hi[2] = __builtin_amdgcn_perm(b[1], b[0], 0x07060302u);
    hi[3] = __builtin_amdgcn_perm(b[3], b[2], 0x07060302u);
    lo[0] = __builtin_amdgcn_perm(a[1], a[0], 0x05040100u);
    lo[1] = __builtin_amdgcn_perm(a[3], a[2], 0x05040100u);
    lo[2] = __builtin_amdgcn_perm(b[1], b[0], 0x05040100u);
    lo[3] = __builtin_amdgcn_perm(b[3], b[2], 0x05040100u);
}

// A/B fragment for mfma_f32_16x16x32_bf16: lane l holds 8 consecutive k at
// k0 + (l>>4)*8, row/col = l&15.  LDS tiles are packed u32 with 16B-slot
// XOR swizzle: slot' = slot ^ (row & 15)  (conflict-free frag reads/writes).
__device__ __forceinline__ void lds_frag(const unsigned int* base, int stride,
                                         int row, int k0, int lhi,
                                         u32x4& hi, u32x4& lo) {
    int s0 = (k0 >> 2) + lhi * 2;
    int m = row & 15;
    const unsigned int* rp = base + row * stride;
    u32x4 a = *(const u32x4*)(rp + (((s0)     ^ m) << 2));
    u32x4 b = *(const u32x4*)(rp + (((s0 + 1) ^ m) << 2));
    unpack8(a, b, hi, lo);
}

__device__ __forceinline__ void glb_frag(const unsigned int* W, int stride,
                                         int row, int k0, int lhi,
                                         u32x4& hi, u32x4& lo) {
    const u32x4* q = (const u32x4*)(W + (size_t)row * stride + k0 + lhi * 8);
    u32x4 a = q[0], b = q[1];
    unpack8(a, b, hi, lo);
}

#define MFMA(A, B, C) __builtin_amdgcn_mfma_f32_16x16x32_bf16( \
    __builtin_bit_cast(bf16x8, A), __builtin_bit_cast(bf16x8, B), C, 0, 0, 0)

// ---- one-off weight conversion: fp32 -> packed (hi|lo) bf16 ----
__global__ __launch_bounds__(256) void convert_weights(
    const float* __restrict__ Wq, const float* __restrict__ Wo,
    unsigned int* __restrict__ wq_pk, unsigned int* __restrict__ wo_pk) {
    int idx = blockIdx.x * 256 + threadIdx.x;
    if (idx < 768 * 256) wq_pk[idx] = pack_hl(Wq[idx]);
    if (idx < 256 * 256) wo_pk[idx] = pack_hl(Wo[idx]);
}

// ---- word level: 1 block = 1 sequence, 512 threads = 8 waves ----
__global__ __launch_bounds__(512, 2) void word_mfma(
    const float* __restrict__ x,          // [2048][64][256]
    const int*   __restrict__ am,         // [2048][64]
    const unsigned int* __restrict__ Wq,  // [768][256] packed
    const float* __restrict__ bqkv,       // [768]
    const unsigned int* __restrict__ Wo,  // [256][256] packed
    const float* __restrict__ bo,         // [256]
    float* __restrict__ outp,             // [2048][256]
    float* __restrict__ smask)            // [2048]
{
    __shared__ __align__(16) unsigned int xs[64 * 256];  // packed x, swizzled
    __shared__ __align__(16) unsigned int Qs[64 * 64];   // Q, later P
    __shared__ __align__(16) unsigned int Ks[64 * 64];   // K, later O
    __shared__ __align__(16) unsigned int Vt[64 * 64];   // V transposed [d][i]
    __shared__ float msk[64];
    __shared__ float smsum;
    float* pool = (float*)xs;                            // [4][256], aliases xs

    const int t   = threadIdx.x;
    const int w   = t >> 6;          // wave 0..7
    const int l   = t & 63;
    const int l15 = l & 15;
    const int lhi = l >> 4;          // 0..3
    const int sm  = w & 3;           // this wave's query m-tile
    const int dup = w >> 2;          // 0/1: n-half for PV / out-proj
    const int b   = blockIdx.x;
    const float* xb = x + (size_t)b * (64 * 256);

    if (t < 64) msk[t] = (float)am[b * 64 + t];
    // stage x: 4096 float4 / 512 thr = 8 each; pack hi/lo, swizzled b128 write
    #pragma unroll
    for (int i = 0; i < 8; ++i) {
        int f4 = i * 512 + t;
        int row = f4 >> 6, c4 = f4 & 63;
        float4 v = *(const float4*)(xb + row * 256 + c4 * 4);
        u32x4 p;
        p[0] = pack_hl(v.x); p[1] = pack_hl(v.y);
        p[2] = pack_hl(v.z); p[3] = pack_hl(v.w);
        *(u32x4*)(xs + row * 256 + ((c4 ^ (row & 15)) << 2)) = p;
    }
    __syncthreads();
    if (t == 0) { float s = 0.f; for (int i = 0; i < 64; ++i) s += msk[i]; smsum = s; }

    f32x4 oacc[8];
    #pragma unroll
    for (int i = 0; i < 8; ++i) oacc[i] = f32x4{0.f, 0.f, 0.f, 0.f};

    for (int h = 0; h < 4; ++h) {
        // ---------- QKV: 48 (mat,mtile,ntile) units, 6 per wave ----------
        for (int j = 0; j < 6; ++j) {
            int u   = w * 6 + j;
            int mat = u >> 4;            // 0=Q 1=K 2=V
            int rem = u & 15;
            int mt  = rem >> 2, nt = rem & 3;
            int wrow = mat * 256 + h * 64 + nt * 16 + l15;
            int arow = mt * 16 + l15;
            f32x4 ahh = f32x4{0,0,0,0}, ahl = f32x4{0,0,0,0}, alh = f32x4{0,0,0,0};
            for (int k0 = 0; k0 < 256; k0 += 32) {
                u32x4 xh, xl, wh, wl;
                lds_frag(xs, 256, arow, k0, lhi, xh, xl);
                glb_frag(Wq, 256, wrow, k0, lhi, wh, wl);
                ahh = MFMA(xh, wh, ahh);
                ahl = MFMA(xh, wl, ahl);
                alh = MFMA(xl, wh, alh);
            }
            float bias = bqkv[mat * 256 + h * 64 + nt * 16 + l15];
            if (mat == 2) {
                // V -> Vt[d][i]: lane: d = nt*16+l15, i = mt*16+lhi*4+r (contig b128)
                u32x4 pv;
                #pragma unroll
                for (int r = 0; r < 4; ++r) pv[r] = pack_hl(ahh[r] + ahl[r] + alh[r] + bias);
                int d = nt * 16 + l15;
                int c4 = mt * 4 + lhi;
                *(u32x4*)(Vt + d * 64 + ((c4 ^ (d & 15)) << 2)) = pv;
            } else {
                unsigned int* dst = (mat == 0) ? Qs : Ks;
                #pragma unroll
                for (int r = 0; r < 4; ++r) {
                    int row = mt * 16 + lhi * 4 + r;
                    int col = nt * 16 + l15;
                    dst[row * 64 + (((col >> 2) ^ (row & 15)) << 2) + (col & 3)] =
                        pack_hl(ahh[r] + ahl[r] + alh[r] + bias);
                }
            }
        }
        __syncthreads();

        // ---------- scores + softmax + P write (waves 0-3 only) ----------
        if (dup == 0) {
            f32x4 sa[4];
            #pragma unroll
            for (int i = 0; i < 4; ++i) sa[i] = f32x4{0,0,0,0};
            for (int k0 = 0; k0 < 64; k0 += 32) {
                u32x4 qh, ql;
                lds_frag(Qs, 64, sm * 16 + l15, k0, lhi, qh, ql);
                #pragma unroll
                for (int nt = 0; nt < 4; ++nt) {
                    u32x4 kh, kl;
                    lds_frag(Ks, 64, nt * 16 + l15, k0, lhi, kh, kl);
                    sa[nt] = MFMA(qh, kh, sa[nt]);
                    sa[nt] = MFMA(qh, kl, sa[nt]);
                    sa[nt] = MFMA(ql, kh, sa[nt]);
                }
            }
            float sc[4][4];
            #pragma unroll
            for (int nt = 0; nt < 4; ++nt) {
                float mterm = (1.0f - msk[nt * 16 + l15]) * -1e9f;
                #pragma unroll
                for (int r = 0; r < 4; ++r) sc[nt][r] = sa[nt][r] * 0.125f + mterm;
            }
            // softmax per query row r (16 lanes x 4 ntiles hold its 64 scores)
            #pragma unroll
            for (int r = 0; r < 4; ++r) {
                float m = fmaxf(fmaxf(sc[0][r], sc[1][r]), fmaxf(sc[2][r], sc[3][r]));
                #pragma unroll
                for (int off = 1; off < 16; off <<= 1) m = fmaxf(m, __shfl_xor(m, off));
                float e0 = expf(sc[0][r] - m), e1 = expf(sc[1][r] - m);
                float e2 = expf(sc[2][r] - m), e3 = expf(sc[3][r] - m);
                float s = e0 + e1 + e2 + e3;
                #pragma unroll
                for (int off = 1; off < 16; off <<= 1) s += __shfl_xor(s, off);
                float inv = 1.0f / s;
                sc[0][r] = e0 * inv; sc[1][r] = e1 * inv;
                sc[2][r] = e2 * inv; sc[3][r] = e3 * inv;
            }
            // P -> Qs (own rows only; Q dead for this wave)
            #pragma unroll
            for (int nt = 0; nt < 4; ++nt) {
                #pragma unroll
                for (int r = 0; r < 4; ++r) {
                    int row = sm * 16 + lhi * 4 + r;
                    int col = nt * 16 + l15;
                    Qs[row * 64 + (((col >> 2) ^ (row & 15)) << 2) + (col & 3)] =
                        pack_hl(sc[nt][r]);
                }
            }
        }
        __syncthreads();

        // ---------- PV: wave = (mtile sm, d-tiles dup*2 + {0,1}) ----------
        {
            f32x4 phh[2], phl[2], plh[2];
            #pragma unroll
            for (int i = 0; i < 2; ++i) {
                phh[i] = f32x4{0,0,0,0}; phl[i] = f32x4{0,0,0,0}; plh[i] = f32x4{0,0,0,0};
            }
            for (int k0 = 0; k0 < 64; k0 += 32) {
                u32x4 ph, pl;
                lds_frag(Qs, 64, sm * 16 + l15, k0, lhi, ph, pl);
                #pragma unroll
                for (int n2 = 0; n2 < 2; ++n2) {
                    int nt = dup * 2 + n2;
                    u32x4 vh, vl;
                    lds_frag(Vt, 64, nt * 16 + l15, k0, lhi, vh, vl);
                    phh[n2] = MFMA(ph, vh, phh[n2]);
                    phl[n2] = MFMA(ph, vl, phl[n2]);
                    plh[n2] = MFMA(pl, vh, plh[n2]);
                }
            }
            __syncthreads();   // all reads of Ks(scores)/Qs done; now O -> Ks
            #pragma unroll
            for (int n2 = 0; n2 < 2; ++n2) {
                #pragma unroll
                for (int r = 0; r < 4; ++r) {
                    int row = sm * 16 + lhi * 4 + r;
                    int col = (dup * 2 + n2) * 16 + l15;
                    Ks[row * 64 + (((col >> 2) ^ (row & 15)) << 2) + (col & 3)] =
                        pack_hl(phh[n2][r] + phl[n2][r] + plh[n2][r]);
                }
            }
        }
        __syncthreads();

        // ---------- out-proj partial: C[q][ocol] += O_h @ Wo_h^T ----------
        for (int k0 = 0; k0 < 64; k0 += 32) {
            u32x4 oh, ol;
            lds_frag(Ks, 64, sm * 16 + l15, k0, lhi, oh, ol);
            #pragma unroll
            for (int nt = 0; nt < 8; ++nt) {
                int ocol = dup * 128 + nt * 16 + l15;
                u32x4 wh, wl;
                glb_frag(Wo, 256, ocol, h * 64 + k0, lhi, wh, wl);
                oacc[nt] = MFMA(oh, wh, oacc[nt]);
                oacc[nt] = MFMA(oh, wl, oacc[nt]);
                oacc[nt] = MFMA(ol, wh, oacc[nt]);
            }
        }
        __syncthreads();   // before next head's QKV overwrites tiles
    }

    // ---------- masked mean pool ----------
    float part[8];
    #pragma unroll
    for (int nt = 0; nt < 8; ++nt) {
        float s = 0.f;
        #pragma unroll
        for (int r = 0; r < 4; ++r) s += msk[sm * 16 + lhi * 4 + r] * oacc[nt][r];
        s += __shfl_xor(s, 16);
        s += __shfl_xor(s, 32);
        part[nt] = s;
    }
    if (lhi == 0) {
        #pragma unroll
        for (int nt = 0; nt < 8; ++nt)
            pool[sm * 256 + dup * 128 + nt * 16 + l15] = part[nt];
    }
    __syncthreads();
    if (t < 256) {
        float s = pool[t] + pool[256 + t] + pool[512 + t] + pool[768 + t];
        float m = smsum;
        outp[(size_t)b * 256 + t] = (s + bo[t] * m) / (m + 1e-10f);
    }
    if (t == 0) smask[b] = (smsum > 0.f) ? 1.f : 0.f;
}

// ---- levels 2/3: small-L fp32 path (unchanged) ----
template <int L>
__global__ __launch_bounds__(256) void pool_kernel(
    const float* __restrict__ xin, const float* __restrict__ mk,
    const float* __restrict__ Wqkv, const float* __restrict__ bqkv,
    const float* __restrict__ Wo,   const float* __restrict__ bo,
    float* __restrict__ outp, float* __restrict__ outmask)
{
    __shared__ __align__(16) float Xs[L * 260];
    __shared__ __align__(16) float QKV[L * 772];
    __shared__ float At[4 * L * (L + 1)];
    __shared__ __align__(16) float Oh[L * 260];
    __shared__ float msk[L];
    __shared__ float smsum;

    const int t = threadIdx.x, b = blockIdx.x;
    const float* xb = xin + (size_t)b * L * 256;

    for (int idx = t; idx < L * 256; idx += 256)
        Xs[(idx >> 8) * 260 + (idx & 255)] = xb[idx];
    if (t < L) msk[t] = mk[b * L + t];
    __syncthreads();
    if (t == 0) { float s = 0.f; for (int i = 0; i < L; ++i) s += msk[i]; smsum = s; }

    for (int idx = t; idx < L * 768; idx += 256) {
        int l = idx / 768, col = idx - l * 768;
        const float* xr = Xs + l * 260;
        const float* wr = Wqkv + (size_t)col * 256;
        float s = bqkv[col];
        for (int c = 0; c < 256; c += 4) {
            float4 xv = *(const float4*)(xr + c);
            float4 wv = *(const float4*)(wr + c);
            s += xv.x * wv.x + xv.y * wv.y + xv.z * wv.z + xv.w * wv.w;
        }
        QKV[l * 772 + col] = s;
    }
    __syncthreads();

    if (t < 4 * L) {
        int h = t / L, i = t - h * L;
        float sc[L];
        float m = -3.4e38f;
        #pragma unroll
        for (int j = 0; j < L; ++j) {
            const float* qr = QKV + i * 772 + h * 64;
            const float* kr = QKV + j * 772 + 256 + h * 64;
            float s = 0.f;
            for (int d = 0; d < 64; d += 4) {
                float4 qv = *(const float4*)(qr + d);
                float4 kv = *(const float4*)(kr + d);
                s += qv.x * kv.x + qv.y * kv.y + qv.z * kv.z + qv.w * kv.w;
            }
            s = s * 0.125f + (1.0f - msk[j]) * (-1e9f);
            sc[j] = s; m = fmaxf(m, s);
        }
        float sum = 0.f;
        #pragma unroll
        for (int j = 0; j < L; ++j) { float e = expf(sc[j] - m); sc[j] = e; sum += e; }
        float inv = 1.0f / sum;
        #pragma unroll
        for (int j = 0; j < L; ++j) At[(h * L + i) * (L + 1) + j] = sc[j] * inv;
    }
    __syncthreads();

    for (int idx = t; idx < L * 256; idx += 256) {
        int l = idx >> 8, d8 = idx & 255;
        int h = d8 >> 6, d = d8 & 63;
        float s = 0.f;
        #pragma unroll
        for (int j = 0; j < L; ++j)
            s += At[(h * L + l) * (L + 1) + j] * QKV[j * 772 + 512 + h * 64 + d];
        Oh[l * 260 + d8] = s;
    }
    __syncthreads();

    {
        int j = t;
        const float* wr = Wo + (size_t)j * 256;
        float bj = bo[j];
        float accp = 0.f;
        for (int l = 0; l < L; ++l) {
            const float* orow = Oh + l * 260;
            float s = 0.f;
            for (int c = 0; c < 256; c += 4) {
                float4 ov = *(const float4*)(orow + c);
                float4 wv = *(const float4*)(wr + c);
                s += ov.x * wv.x + ov.y * wv.y + ov.z * wv.z + ov.w * wv.w;
            }
            accp += (s + bj) * msk[l];
        }
        float msum = smsum;
        outp[(size_t)b * 256 + j] = accp / (msum + 1e-10f);
    }
    if (outmask && t == 0) outmask[b] = (smsum > 0.f) ? 1.f : 0.f;
}

extern "C" void kernel_launch(void* const* d_in, const int* in_sizes, int n_in,
                              void* d_out, int out_size, void* d_ws, size_t ws_size,
                              hipStream_t stream) {
    (void)in_sizes; (void)n_in; (void)out_size; (void)ws_size;
    const float* we  = (const float*)d_in[0];
    const int*   am  = (const int*)d_in[1];
    const float* wW  = (const float*)d_in[2];
    const float* wb  = (const float*)d_in[3];
    const float* wO  = (const float*)d_in[4];
    const float* wob = (const float*)d_in[5];
    const float* sW  = (const float*)d_in[6];
    const float* sb  = (const float*)d_in[7];
    const float* sO  = (const float*)d_in[8];
    const float* sob = (const float*)d_in[9];
    const float* cW  = (const float*)d_in[10];
    const float* cb  = (const float*)d_in[11];
    const float* cO  = (const float*)d_in[12];
    const float* cob = (const float*)d_in[13];

    float* ws     = (float*)d_ws;
    float* sentb  = ws;                        // 2048*256
    float* sectb  = sentb + 2048 * 256;        // 128*256
    float* smaskb = sectb + 128 * 256;         // 2048
    float* cmaskb = smaskb + 2048;             // 128
    unsigned int* wq_pk = (unsigned int*)(cmaskb + 128);   // 768*256
    unsigned int* wo_pk = wq_pk + 768 * 256;               // 256*256

    convert_weights<<<768, 256, 0, stream>>>(wW, wO, wq_pk, wo_pk);
    word_mfma<<<2048, 512, 0, stream>>>(we, am, wq_pk, wb, wo_pk, wob, sentb, smaskb);
    pool_kernel<16><<<128, 256, 0, stream>>>(sentb, smaskb, sW, sb, sO, sob, sectb, cmaskb);
    pool_kernel<8><<<16, 256, 0, stream>>>(sectb, cmaskb, cW, cb, cO, cob, (float*)d_out, nullptr);
}

// Round 6
// 1047.958 us; speedup vs baseline: 4.6265x; 1.5560x over previous
//
#include <hip/hip_runtime.h>
#include <hip/hip_bf16.h>

// Hierarchical attention, 3 levels, all GEMM phases on split-bf16 MFMA:
// value = hi + lo (two bf16); every product = 3x mfma_f32_16x16x32_bf16
// (hi*hi + hi*lo + lo*hi), ~fp32 precision at matrix-core rate.
// All operands stored as SEPARATE hi/lo bf16 planes (no pack/unpack perms).

typedef short bf16x8 __attribute__((ext_vector_type(8)));
typedef float f32x4 __attribute__((ext_vector_type(4)));
typedef unsigned int u32x4 __attribute__((ext_vector_type(4)));
typedef unsigned short U16;
typedef unsigned int U32;

__device__ __forceinline__ U32 bf16_rne(float f) {
    U32 u = __builtin_bit_cast(U32, f);
    return (u + 0x7FFFu + ((u >> 16) & 1u)) >> 16;
}
__device__ __forceinline__ void split_hl(float f, U16& h, U16& l) {
    U32 hu = bf16_rne(f);
    float hf = __builtin_bit_cast(float, hu << 16);
    h = (U16)hu;
    l = (U16)bf16_rne(f - hf);
}

#define MFMA(A, B, C) __builtin_amdgcn_mfma_f32_16x16x32_bf16( \
    __builtin_bit_cast(bf16x8, A), __builtin_bit_cast(bf16x8, B), C, 0, 0, 0)

// LDS plane fragment read. RS = row stride (u16 units), SW = swizzle mask.
// Element k of row r lives at slot ((k>>3) ^ (r & SW)) (16B slots).
template <int RS, int SW>
__device__ __forceinline__ u32x4 fragp(const U16* base, int row, int k, int lhi) {
    int slot = ((k >> 3) + lhi) ^ (row & SW);
    return *(const u32x4*)(base + row * RS + slot * 8);
}
template <int RS, int SW>
__device__ __forceinline__ void put16(U16* base, int row, int col, U16 v) {
    int slot = (col >> 3) ^ (row & SW);
    base[row * RS + slot * 8 + (col & 7)] = v;
}
template <int RS, int SW>
__device__ __forceinline__ void put64(U16* base, int row, int col0,
                                      U16 v0, U16 v1, U16 v2, U16 v3) {
    int slot = (col0 >> 3) ^ (row & SW);
    U32* p = (U32*)(base + row * RS + slot * 8 + (col0 & 7));
    p[0] = (U32)v0 | ((U32)v1 << 16);
    p[1] = (U32)v2 | ((U32)v3 << 16);
}

// ---- one-off weight conversion: fp32 -> hi/lo bf16 planes ----
__global__ __launch_bounds__(256) void convert_w(
    const float* __restrict__ Wq, const float* __restrict__ Wo,
    U16* __restrict__ qh, U16* __restrict__ ql,
    U16* __restrict__ oh, U16* __restrict__ ol)
{
    int i = blockIdx.x * 256 + threadIdx.x;
    if (i < 768 * 256) { U16 h, l; split_hl(Wq[i], h, l); qh[i] = h; ql[i] = l; }
    if (i < 256 * 256) { U16 h, l; split_hl(Wo[i], h, l); oh[i] = h; ol[i] = l; }
}

// ---- word level: 1 block = 1 sequence (L=64), 512 threads = 8 waves ----
__global__ __launch_bounds__(512, 2) void word_mfma(
    const float* __restrict__ x, const int* __restrict__ am,
    const U16* __restrict__ Wqh, const U16* __restrict__ Wql,
    const float* __restrict__ bqkv,
    const U16* __restrict__ Woh, const U16* __restrict__ Wol,
    const float* __restrict__ bo,
    U16* __restrict__ sent_hi, U16* __restrict__ sent_lo,
    float* __restrict__ smask)
{
    __shared__ __align__(16) U16 xs_h[64 * 256];  // 32 KB
    __shared__ __align__(16) U16 xs_l[64 * 256];  // 32 KB
    __shared__ __align__(16) U16 Qh_[64 * 64];    // Q, later P
    __shared__ __align__(16) U16 Ql_[64 * 64];
    __shared__ __align__(16) U16 Kh_[64 * 64];    // K, later O
    __shared__ __align__(16) U16 Kl_[64 * 64];
    __shared__ __align__(16) U16 Vh_[64 * 64];    // V transposed [d][j]
    __shared__ __align__(16) U16 Vl_[64 * 64];
    __shared__ float msk[64];
    __shared__ float smsum;
    float* pool = (float*)xs_h;   // [512] floats, aliases xs (dead by then)

    const int t = threadIdx.x;
    const int w = t >> 6, l = t & 63, l15 = l & 15, lhi = l >> 4;
    const int b = blockIdx.x;
    const float* xb = x + (size_t)b * 16384;

    if (t < 64) msk[t] = (float)am[b * 64 + t];

    // stage x -> split planes (swizzled); 2048 chunks of 8 elems, 4/thread
    #pragma unroll
    for (int i = 0; i < 4; ++i) {
        int c = i * 512 + t;
        int row = c >> 5, c8 = c & 31;
        const float* p = xb + row * 256 + c8 * 8;
        float4 f0 = *(const float4*)p;
        float4 f1 = *(const float4*)(p + 4);
        U16 hh[8], ll[8];
        split_hl(f0.x, hh[0], ll[0]); split_hl(f0.y, hh[1], ll[1]);
        split_hl(f0.z, hh[2], ll[2]); split_hl(f0.w, hh[3], ll[3]);
        split_hl(f1.x, hh[4], ll[4]); split_hl(f1.y, hh[5], ll[5]);
        split_hl(f1.z, hh[6], ll[6]); split_hl(f1.w, hh[7], ll[7]);
        u32x4 hv, lv;
        #pragma unroll
        for (int q = 0; q < 4; ++q) {
            hv[q] = (U32)hh[2*q] | ((U32)hh[2*q+1] << 16);
            lv[q] = (U32)ll[2*q] | ((U32)ll[2*q+1] << 16);
        }
        int slot = c8 ^ (row & 7);
        *(u32x4*)(xs_h + row * 256 + slot * 8) = hv;
        *(u32x4*)(xs_l + row * 256 + slot * 8) = lv;
    }
    __syncthreads();
    if (t == 0) { float s = 0.f; for (int i = 0; i < 64; ++i) s += msk[i]; smsum = s; }

    f32x4 oacc[8];
    #pragma unroll
    for (int i = 0; i < 8; ++i) oacc[i] = f32x4{0.f, 0.f, 0.f, 0.f};

    const int sm = w & 3, dup = w >> 2;

    for (int h = 0; h < 4; ++h) {
        // ------- QKV: waves 0-3 Q(nt), 4-7 K(nt), + 2 V units each -------
        {
            const int mat = w >> 2, nt = w & 3;
            const int vnt = w >> 1;
            const int vm0 = (2 * w) & 3, vm1 = (2 * w + 1) & 3;
            const U16* WAh = Wqh + (size_t)(mat*256 + h*64 + nt*16 + l15) * 256;
            const U16* WAl = Wql + (size_t)(mat*256 + h*64 + nt*16 + l15) * 256;
            const U16* WVh = Wqh + (size_t)(512 + h*64 + vnt*16 + l15) * 256;
            const U16* WVl = Wql + (size_t)(512 + h*64 + vnt*16 + l15) * 256;
            f32x4 acc[4], vacc[2];
            #pragma unroll
            for (int i = 0; i < 4; ++i) acc[i] = f32x4{0.f,0.f,0.f,0.f};
            vacc[0] = f32x4{0.f,0.f,0.f,0.f}; vacc[1] = f32x4{0.f,0.f,0.f,0.f};
            #pragma unroll
            for (int k0 = 0; k0 < 256; k0 += 32) {
                u32x4 wh = *(const u32x4*)(WAh + k0 + lhi * 8);
                u32x4 wl = *(const u32x4*)(WAl + k0 + lhi * 8);
                u32x4 vh = *(const u32x4*)(WVh + k0 + lhi * 8);
                u32x4 vl = *(const u32x4*)(WVl + k0 + lhi * 8);
                u32x4 ah[4], al[4];
                #pragma unroll
                for (int mt = 0; mt < 4; ++mt) {
                    ah[mt] = fragp<256,7>(xs_h, mt*16 + l15, k0, lhi);
                    al[mt] = fragp<256,7>(xs_l, mt*16 + l15, k0, lhi);
                }
                #pragma unroll
                for (int mt = 0; mt < 4; ++mt) {
                    acc[mt] = MFMA(ah[mt], wh, acc[mt]);
                    acc[mt] = MFMA(ah[mt], wl, acc[mt]);
                    acc[mt] = MFMA(al[mt], wh, acc[mt]);
                }
                vacc[0] = MFMA(ah[vm0], vh, vacc[0]);
                vacc[0] = MFMA(ah[vm0], vl, vacc[0]);
                vacc[0] = MFMA(al[vm0], vh, vacc[0]);
                vacc[1] = MFMA(ah[vm1], vh, vacc[1]);
                vacc[1] = MFMA(ah[vm1], vl, vacc[1]);
                vacc[1] = MFMA(al[vm1], vh, vacc[1]);
            }
            float biasA = bqkv[mat*256 + h*64 + nt*16 + l15];
            U16* dh = (mat == 0) ? Qh_ : Kh_;
            U16* dl = (mat == 0) ? Ql_ : Kl_;
            #pragma unroll
            for (int mt = 0; mt < 4; ++mt) {
                #pragma unroll
                for (int r = 0; r < 4; ++r) {
                    U16 vH, vL; split_hl(acc[mt][r] + biasA, vH, vL);
                    put16<64,7>(dh, mt*16 + lhi*4 + r, nt*16 + l15, vH);
                    put16<64,7>(dl, mt*16 + lhi*4 + r, nt*16 + l15, vL);
                }
            }
            float biasV = bqkv[512 + h*64 + vnt*16 + l15];
            {
                U16 h4[4], l4[4];
                #pragma unroll
                for (int r = 0; r < 4; ++r) split_hl(vacc[0][r] + biasV, h4[r], l4[r]);
                put64<64,7>(Vh_, vnt*16 + l15, vm0*16 + lhi*4, h4[0],h4[1],h4[2],h4[3]);
                put64<64,7>(Vl_, vnt*16 + l15, vm0*16 + lhi*4, l4[0],l4[1],l4[2],l4[3]);
                #pragma unroll
                for (int r = 0; r < 4; ++r) split_hl(vacc[1][r] + biasV, h4[r], l4[r]);
                put64<64,7>(Vh_, vnt*16 + l15, vm1*16 + lhi*4, h4[0],h4[1],h4[2],h4[3]);
                put64<64,7>(Vl_, vnt*16 + l15, vm1*16 + lhi*4, l4[0],l4[1],l4[2],l4[3]);
            }
        }
        __syncthreads();

        // ------- scores + softmax + P (waves 0-3) -------
        if (dup == 0) {
            f32x4 sa[4];
            #pragma unroll
            for (int i = 0; i < 4; ++i) sa[i] = f32x4{0.f,0.f,0.f,0.f};
            #pragma unroll
            for (int k0 = 0; k0 < 64; k0 += 32) {
                u32x4 qh = fragp<64,7>(Qh_, sm*16 + l15, k0, lhi);
                u32x4 ql = fragp<64,7>(Ql_, sm*16 + l15, k0, lhi);
                #pragma unroll
                for (int nt = 0; nt < 4; ++nt) {
                    u32x4 kh = fragp<64,7>(Kh_, nt*16 + l15, k0, lhi);
                    u32x4 kl = fragp<64,7>(Kl_, nt*16 + l15, k0, lhi);
                    sa[nt] = MFMA(qh, kh, sa[nt]);
                    sa[nt] = MFMA(qh, kl, sa[nt]);
                    sa[nt] = MFMA(ql, kh, sa[nt]);
                }
            }
            float sc[4][4];
            #pragma unroll
            for (int nt = 0; nt < 4; ++nt) {
                float mterm = (1.0f - msk[nt*16 + l15]) * -1e9f;
                #pragma unroll
                for (int r = 0; r < 4; ++r) sc[nt][r] = sa[nt][r] * 0.125f + mterm;
            }
            #pragma unroll
            for (int r = 0; r < 4; ++r) {
                float m = fmaxf(fmaxf(sc[0][r], sc[1][r]), fmaxf(sc[2][r], sc[3][r]));
                #pragma unroll
                for (int off = 1; off < 16; off <<= 1) m = fmaxf(m, __shfl_xor(m, off));
                float e0 = expf(sc[0][r]-m), e1 = expf(sc[1][r]-m);
                float e2 = expf(sc[2][r]-m), e3 = expf(sc[3][r]-m);
                float s = e0 + e1 + e2 + e3;
                #pragma unroll
                for (int off = 1; off < 16; off <<= 1) s += __shfl_xor(s, off);
                float inv = 1.0f / s;
                sc[0][r]=e0*inv; sc[1][r]=e1*inv; sc[2][r]=e2*inv; sc[3][r]=e3*inv;
            }
            #pragma unroll
            for (int nt = 0; nt < 4; ++nt) {
                #pragma unroll
                for (int r = 0; r < 4; ++r) {
                    U16 vH, vL; split_hl(sc[nt][r], vH, vL);
                    put16<64,7>(Qh_, sm*16 + lhi*4 + r, nt*16 + l15, vH);
                    put16<64,7>(Ql_, sm*16 + lhi*4 + r, nt*16 + l15, vL);
                }
            }
        }
        __syncthreads();

        // ------- PV (all 8 waves), O -> K planes -------
        {
            f32x4 pa[2];
            pa[0] = f32x4{0.f,0.f,0.f,0.f}; pa[1] = f32x4{0.f,0.f,0.f,0.f};
            #pragma unroll
            for (int k0 = 0; k0 < 64; k0 += 32) {
                u32x4 ph = fragp<64,7>(Qh_, sm*16 + l15, k0, lhi);
                u32x4 pl = fragp<64,7>(Ql_, sm*16 + l15, k0, lhi);
                #pragma unroll
                for (int n2 = 0; n2 < 2; ++n2) {
                    int nt = dup*2 + n2;
                    u32x4 vh = fragp<64,7>(Vh_, nt*16 + l15, k0, lhi);
                    u32x4 vl = fragp<64,7>(Vl_, nt*16 + l15, k0, lhi);
                    pa[n2] = MFMA(ph, vh, pa[n2]);
                    pa[n2] = MFMA(ph, vl, pa[n2]);
                    pa[n2] = MFMA(pl, vh, pa[n2]);
                }
            }
            #pragma unroll
            for (int n2 = 0; n2 < 2; ++n2) {
                #pragma unroll
                for (int r = 0; r < 4; ++r) {
                    U16 vH, vL; split_hl(pa[n2][r], vH, vL);
                    put16<64,7>(Kh_, sm*16 + lhi*4 + r, (dup*2+n2)*16 + l15, vH);
                    put16<64,7>(Kl_, sm*16 + lhi*4 + r, (dup*2+n2)*16 + l15, vL);
                }
            }
        }
        __syncthreads();

        // ------- out-proj: wave = (row-pair smp, col-quarter ocq) -------
        {
            const int smp = w & 1, ocq = w >> 1;
            #pragma unroll
            for (int k0 = 0; k0 < 64; k0 += 32) {
                u32x4 oh0 = fragp<64,7>(Kh_, (smp*2+0)*16 + l15, k0, lhi);
                u32x4 ol0 = fragp<64,7>(Kl_, (smp*2+0)*16 + l15, k0, lhi);
                u32x4 oh1 = fragp<64,7>(Kh_, (smp*2+1)*16 + l15, k0, lhi);
                u32x4 ol1 = fragp<64,7>(Kl_, (smp*2+1)*16 + l15, k0, lhi);
                #pragma unroll
                for (int j = 0; j < 4; ++j) {
                    int oc = ocq*64 + j*16 + l15;
                    u32x4 wh = *(const u32x4*)(Woh + (size_t)oc*256 + h*64 + k0 + lhi*8);
                    u32x4 wl = *(const u32x4*)(Wol + (size_t)oc*256 + h*64 + k0 + lhi*8);
                    oacc[j] = MFMA(oh0, wh, oacc[j]);
                    oacc[j] = MFMA(oh0, wl, oacc[j]);
                    oacc[j] = MFMA(ol0, wh, oacc[j]);
                    oacc[4+j] = MFMA(oh1, wh, oacc[4+j]);
                    oacc[4+j] = MFMA(oh1, wl, oacc[4+j]);
                    oacc[4+j] = MFMA(ol1, wh, oacc[4+j]);
                }
            }
        }
        __syncthreads();
    }

    // ------- masked mean pool -------
    {
        const int smp = w & 1, ocq = w >> 1;
        float colsum[4];
        #pragma unroll
        for (int j = 0; j < 4; ++j) {
            float s = 0.f;
            #pragma unroll
            for (int r = 0; r < 4; ++r) {
                s += msk[(smp*2+0)*16 + lhi*4 + r] * oacc[j][r];
                s += msk[(smp*2+1)*16 + lhi*4 + r] * oacc[4+j][r];
            }
            s += __shfl_xor(s, 16);
            s += __shfl_xor(s, 32);
            colsum[j] = s;
        }
        if (lhi == 0) {
            #pragma unroll
            for (int j = 0; j < 4; ++j)
                pool[smp*256 + ocq*64 + j*16 + l15] = colsum[j];
        }
    }
    __syncthreads();
    if (t < 256) {
        float s = pool[t] + pool[256 + t];
        float m = smsum;
        float val = (s + bo[t] * m) / (m + 1e-10f);
        U16 vH, vL; split_hl(val, vH, vL);
        sent_hi[(size_t)b * 256 + t] = vH;
        sent_lo[(size_t)b * 256 + t] = vL;
    }
    if (t == 0) smask[b] = (smsum > 0.f) ? 1.f : 0.f;
}

// ---- levels 2/3: L in {16, 8}; 256 threads = 4 waves, wave = head ----
template <int L>
__global__ __launch_bounds__(256) void mha_small(
    const U16* __restrict__ xh, const U16* __restrict__ xl,  // [N*L][256]
    const float* __restrict__ mk,                            // [N*L]
    const U16* __restrict__ Wqh, const U16* __restrict__ Wql,
    const float* __restrict__ bqkv,
    const U16* __restrict__ Woh, const U16* __restrict__ Wol,
    const float* __restrict__ bo,
    float* __restrict__ out_f32, U16* __restrict__ out_hi, U16* __restrict__ out_lo,
    float* __restrict__ outmask)
{
    __shared__ __align__(16) U16 xs_h[16*256], xs_l[16*256];
    __shared__ __align__(16) U16 Qh_[16*256], Ql_[16*256];
    __shared__ __align__(16) U16 Kh_[16*256], Kl_[16*256];
    __shared__ __align__(16) U16 Vh_[256*32], Vl_[256*32];   // [d][j], j padded to 32
    __shared__ __align__(16) U16 Ph_[4][16*32], Pl_[4][16*32];
    __shared__ __align__(16) U16 Oh_[16*256], Ol_[16*256];
    __shared__ float msk[16];
    __shared__ float smsum;

    const int t = threadIdx.x;
    const int w = t >> 6, l = t & 63, l15 = l & 15, lhi = l >> 4;
    const int b = blockIdx.x;

    if (t < 16) msk[t] = (t < L) ? mk[b*L + t] : 0.f;

    // stage x (rows >= L zeroed)
    #pragma unroll
    for (int i = 0; i < 2; ++i) {
        int c = i*256 + t;
        int row = c >> 5, c8 = c & 31;
        u32x4 hv = u32x4{0,0,0,0}, lv = u32x4{0,0,0,0};
        if (row < L) {
            hv = *(const u32x4*)(xh + ((size_t)b*L + row)*256 + c8*8);
            lv = *(const u32x4*)(xl + ((size_t)b*L + row)*256 + c8*8);
        }
        int slot = c8 ^ (row & 7);
        *(u32x4*)(xs_h + row*256 + slot*8) = hv;
        *(u32x4*)(xs_l + row*256 + slot*8) = lv;
    }
    // zero V (pad cols stay 0) and P planes
    #pragma unroll
    for (int i = 0; i < 4; ++i) {
        int c = i*256 + t;
        *(u32x4*)(Vh_ + c*8) = u32x4{0,0,0,0};
        *(u32x4*)(Vl_ + c*8) = u32x4{0,0,0,0};
    }
    *(u32x4*)(&Ph_[0][0] + t*8) = u32x4{0,0,0,0};
    *(u32x4*)(&Pl_[0][0] + t*8) = u32x4{0,0,0,0};
    __syncthreads();
    if (t == 0) { float s = 0.f; for (int i = 0; i < 16; ++i) s += msk[i]; smsum = s; }

    // ------- QKV: 48 col-tiles, 12 per wave -------
    {
        f32x4 acc[12];
        #pragma unroll
        for (int i = 0; i < 12; ++i) acc[i] = f32x4{0.f,0.f,0.f,0.f};
        #pragma unroll 2
        for (int k0 = 0; k0 < 256; k0 += 32) {
            u32x4 ah = fragp<256,7>(xs_h, l15, k0, lhi);
            u32x4 al = fragp<256,7>(xs_l, l15, k0, lhi);
            #pragma unroll
            for (int j = 0; j < 12; ++j) {
                int u = w*12 + j;
                u32x4 wh = *(const u32x4*)(Wqh + (size_t)(u*16 + l15)*256 + k0 + lhi*8);
                u32x4 wl = *(const u32x4*)(Wql + (size_t)(u*16 + l15)*256 + k0 + lhi*8);
                acc[j] = MFMA(ah, wh, acc[j]);
                acc[j] = MFMA(ah, wl, acc[j]);
                acc[j] = MFMA(al, wh, acc[j]);
            }
        }
        #pragma unroll
        for (int j = 0; j < 12; ++j) {
            int u = w*12 + j;
            int mat = u >> 4, cg = u & 15;
            float bias = bqkv[u*16 + l15];
            if (mat < 2) {
                U16* dh = (mat == 0) ? Qh_ : Kh_;
                U16* dl = (mat == 0) ? Ql_ : Kl_;
                #pragma unroll
                for (int r = 0; r < 4; ++r) {
                    U16 vH, vL; split_hl(acc[j][r] + bias, vH, vL);
                    put16<256,7>(dh, lhi*4 + r, cg*16 + l15, vH);
                    put16<256,7>(dl, lhi*4 + r, cg*16 + l15, vL);
                }
            } else {
                U16 h4[4], l4[4];
                #pragma unroll
                for (int r = 0; r < 4; ++r) split_hl(acc[j][r] + bias, h4[r], l4[r]);
                put64<32,3>(Vh_, cg*16 + l15, lhi*4, h4[0],h4[1],h4[2],h4[3]);
                put64<32,3>(Vl_, cg*16 + l15, lhi*4, l4[0],l4[1],l4[2],l4[3]);
            }
        }
    }
    __syncthreads();

    // ------- attention: wave w handles head w end-to-end -------
    {
        const int h = w;
        f32x4 sa = f32x4{0.f,0.f,0.f,0.f};
        #pragma unroll
        for (int k0 = 0; k0 < 64; k0 += 32) {
            u32x4 qh = fragp<256,7>(Qh_, l15, h*64 + k0, lhi);
            u32x4 ql = fragp<256,7>(Ql_, l15, h*64 + k0, lhi);
            u32x4 kh = fragp<256,7>(Kh_, l15, h*64 + k0, lhi);
            u32x4 kl = fragp<256,7>(Kl_, l15, h*64 + k0, lhi);
            sa = MFMA(qh, kh, sa);
            sa = MFMA(qh, kl, sa);
            sa = MFMA(ql, kh, sa);
        }
        float sc[4];
        float mterm = (1.0f - msk[l15]) * -1e9f;
        #pragma unroll
        for (int r = 0; r < 4; ++r) sc[r] = sa[r] * 0.125f + mterm;
        #pragma unroll
        for (int r = 0; r < 4; ++r) {
            float m = sc[r];
            #pragma unroll
            for (int off = 1; off < 16; off <<= 1) m = fmaxf(m, __shfl_xor(m, off));
            float e = expf(sc[r] - m);
            float s = e;
            #pragma unroll
            for (int off = 1; off < 16; off <<= 1) s += __shfl_xor(s, off);
            sc[r] = e / s;
        }
        #pragma unroll
        for (int r = 0; r < 4; ++r) {
            U16 vH, vL; split_hl(sc[r], vH, vL);
            put16<32,3>(&Ph_[h][0], lhi*4 + r, l15, vH);
            put16<32,3>(&Pl_[h][0], lhi*4 + r, l15, vL);
        }
        // PV (K = 32 padded; pad region P=0)
        f32x4 pa[4];
        #pragma unroll
        for (int i = 0; i < 4; ++i) pa[i] = f32x4{0.f,0.f,0.f,0.f};
        {
            u32x4 ph = fragp<32,3>(&Ph_[h][0], l15, 0, lhi);
            u32x4 pl = fragp<32,3>(&Pl_[h][0], l15, 0, lhi);
            #pragma unroll
            for (int ntl = 0; ntl < 4; ++ntl) {
                u32x4 vh = fragp<32,3>(Vh_, h*64 + ntl*16 + l15, 0, lhi);
                u32x4 vl = fragp<32,3>(Vl_, h*64 + ntl*16 + l15, 0, lhi);
                pa[ntl] = MFMA(ph, vh, pa[ntl]);
                pa[ntl] = MFMA(ph, vl, pa[ntl]);
                pa[ntl] = MFMA(pl, vh, pa[ntl]);
            }
        }
        #pragma unroll
        for (int ntl = 0; ntl < 4; ++ntl) {
            #pragma unroll
            for (int r = 0; r < 4; ++r) {
                U16 vH, vL; split_hl(pa[ntl][r], vH, vL);
                put16<256,7>(Oh_, lhi*4 + r, h*64 + ntl*16 + l15, vH);
                put16<256,7>(Ol_, lhi*4 + r, h*64 + ntl*16 + l15, vL);
            }
        }
    }
    __syncthreads();

    // ------- out-proj + pool -------
    {
        f32x4 acc4[4];
        #pragma unroll
        for (int i = 0; i < 4; ++i) acc4[i] = f32x4{0.f,0.f,0.f,0.f};
        #pragma unroll 2
        for (int k0 = 0; k0 < 256; k0 += 32) {
            u32x4 oh = fragp<256,7>(Oh_, l15, k0, lhi);
            u32x4 ol = fragp<256,7>(Ol_, l15, k0, lhi);
            #pragma unroll
            for (int j = 0; j < 4; ++j) {
                int oc = w*64 + j*16 + l15;
                u32x4 wh = *(const u32x4*)(Woh + (size_t)oc*256 + k0 + lhi*8);
                u32x4 wl = *(const u32x4*)(Wol + (size_t)oc*256 + k0 + lhi*8);
                acc4[j] = MFMA(oh, wh, acc4[j]);
                acc4[j] = MFMA(oh, wl, acc4[j]);
                acc4[j] = MFMA(ol, wh, acc4[j]);
            }
        }
        float msum = smsum;
        #pragma unroll
        for (int j = 0; j < 4; ++j) {
            float s = 0.f;
            #pragma unroll
            for (int r = 0; r < 4; ++r) s += msk[lhi*4 + r] * acc4[j][r];
            s += __shfl_xor(s, 16);
            s += __shfl_xor(s, 32);
            if (lhi == 0) {
                int col = w*64 + j*16 + l15;
                float val = (s + bo[col] * msum) / (msum + 1e-10f);
                if (out_f32) out_f32[(size_t)b*256 + col] = val;
                if (out_hi) {
                    U16 vH, vL; split_hl(val, vH, vL);
                    out_hi[(size_t)b*256 + col] = vH;
                    out_lo[(size_t)b*256 + col] = vL;
                }
            }
        }
    }
    if (t == 0 && outmask) outmask[b] = (smsum > 0.f) ? 1.f : 0.f;
}

extern "C" void kernel_launch(void* const* d_in, const int* in_sizes, int n_in,
                              void* d_out, int out_size, void* d_ws, size_t ws_size,
                              hipStream_t stream) {
    (void)in_sizes; (void)n_in; (void)out_size; (void)ws_size;
    const float* we  = (const float*)d_in[0];
    const int*   am  = (const int*)d_in[1];
    const float* wW  = (const float*)d_in[2];
    const float* wb  = (const float*)d_in[3];
    const float* wO  = (const float*)d_in[4];
    const float* wob = (const float*)d_in[5];
    const float* sW  = (const float*)d_in[6];
    const float* sb  = (const float*)d_in[7];
    const float* sO  = (const float*)d_in[8];
    const float* sob = (const float*)d_in[9];
    const float* cW  = (const float*)d_in[10];
    const float* cb  = (const float*)d_in[11];
    const float* cO  = (const float*)d_in[12];
    const float* cob = (const float*)d_in[13];

    U16* p = (U16*)d_ws;
    U16* sent_hi = p; p += 2048*256;
    U16* sent_lo = p; p += 2048*256;
    U16* sect_hi = p; p += 128*256;
    U16* sect_lo = p; p += 128*256;
    U16* w1qh = p; p += 768*256;  U16* w1ql = p; p += 768*256;
    U16* w1oh = p; p += 256*256;  U16* w1ol = p; p += 256*256;
    U16* w2qh = p; p += 768*256;  U16* w2ql = p; p += 768*256;
    U16* w2oh = p; p += 256*256;  U16* w2ol = p; p += 256*256;
    U16* w3qh = p; p += 768*256;  U16* w3ql = p; p += 768*256;
    U16* w3oh = p; p += 256*256;  U16* w3ol = p; p += 256*256;
    float* smaskb = (float*)p;      // counts above are even -> 4B aligned
    float* cmaskb = smaskb + 2048;

    convert_w<<<768, 256, 0, stream>>>(wW, wO, w1qh, w1ql, w1oh, w1ol);
    convert_w<<<768, 256, 0, stream>>>(sW, sO, w2qh, w2ql, w2oh, w2ol);
    convert_w<<<768, 256, 0, stream>>>(cW, cO, w3qh, w3ql, w3oh, w3ol);
    word_mfma<<<2048, 512, 0, stream>>>(we, am, w1qh, w1ql, wb, w1oh, w1ol, wob,
                                        sent_hi, sent_lo, smaskb);
    mha_small<16><<<128, 256, 0, stream>>>(sent_hi, sent_lo, smaskb,
                                           w2qh, w2ql, sb, w2oh, w2ol, sob,
                                           nullptr, sect_hi, sect_lo, cmaskb);
    mha_small<8><<<16, 256, 0, stream>>>(sect_hi, sect_lo, cmaskb,
                                         w3qh, w3ql, cb, w3oh, w3ol, cob,
                                         (float*)d_out, nullptr, nullptr, nullptr);
}

// Round 7
// 919.683 us; speedup vs baseline: 5.2718x; 1.1395x over previous
//
#include <hip/hip_runtime.h>
#include <hip/hip_bf16.h>

// Hierarchical attention, 3 levels, all GEMM phases on split-bf16 MFMA:
// value = hi + lo (two bf16); every product = 3x mfma_f32_16x16x32_bf16
// (hi*hi + hi*lo + lo*hi), ~fp32 precision at matrix-core rate.
// Word level: LDS tiles are PACKED u32 (hi<<16|lo), 256B rows, XOR-16 swizzle
// (r5 geometry, measured 0 bank conflicts); unpack on read via v_perm.
// Weights: global hi/lo bf16 planes. 64.3 KB LDS -> 2 blocks/CU.

typedef short bf16x8 __attribute__((ext_vector_type(8)));
typedef float f32x4 __attribute__((ext_vector_type(4)));
typedef unsigned int u32x4 __attribute__((ext_vector_type(4)));
typedef unsigned short U16;
typedef unsigned int U32;

__device__ __forceinline__ U32 bf16_rne(float f) {
    U32 u = __builtin_bit_cast(U32, f);
    return (u + 0x7FFFu + ((u >> 16) & 1u)) >> 16;
}
__device__ __forceinline__ void split_hl(float f, U16& h, U16& l) {
    U32 hu = bf16_rne(f);
    float hf = __builtin_bit_cast(float, hu << 16);
    h = (U16)hu;
    l = (U16)bf16_rne(f - hf);
}
__device__ __forceinline__ U32 pack_hl(float f) {
    U32 hu = bf16_rne(f);
    float hf = __builtin_bit_cast(float, hu << 16);
    U32 lo = bf16_rne(f - hf);
    return (hu << 16) | (lo & 0xFFFFu);
}

// 8 packed u32 (elems k..k+7) -> hi-fragment (4 u32 = 8 bf16) + lo-fragment
__device__ __forceinline__ void unpack8(u32x4 a, u32x4 b, u32x4& hi, u32x4& lo) {
    hi[0] = __builtin_amdgcn_perm(a[1], a[0], 0x07060302u);
    hi[1] = __builtin_amdgcn_perm(a[3], a[2], 0x07060302u);
    hi[2] = __builtin_amdgcn_perm(b[1], b[0], 0x07060302u);
    hi[3] = __builtin_amdgcn_perm(b[3], b[2], 0x07060302u);
    lo[0] = __builtin_amdgcn_perm(a[1], a[0], 0x05040100u);
    lo[1] = __builtin_amdgcn_perm(a[3], a[2], 0x05040100u);
    lo[2] = __builtin_amdgcn_perm(b[1], b[0], 0x05040100u);
    lo[3] = __builtin_amdgcn_perm(b[3], b[2], 0x05040100u);
}

#define MFMA(A, B, C) __builtin_amdgcn_mfma_f32_16x16x32_bf16( \
    __builtin_bit_cast(bf16x8, A), __builtin_bit_cast(bf16x8, B), C, 0, 0, 0)

// Packed-u32 tile helpers (row stride 64 u32 = 256 B, 16 slots of 16B, XOR-16).
// Element (row,col): tile[row*64 + ((col>>2)^(row&15))*4 + (col&3)].
__device__ __forceinline__ void tile_frag(const U32* tile, int row, int s0,
                                          u32x4& hi, u32x4& lo) {
    int m = row & 15;
    u32x4 a = *(const u32x4*)(tile + row * 64 + ((s0    ) ^ m) * 4);
    u32x4 b = *(const u32x4*)(tile + row * 64 + ((s0 + 1) ^ m) * 4);
    unpack8(a, b, hi, lo);
}
__device__ __forceinline__ void tile_put(U32* tile, int row, int col, float v) {
    tile[row * 64 + (((col >> 2) ^ (row & 15))) * 4 + (col & 3)] = pack_hl(v);
}

// ---- hi/lo plane helpers for mha_small (unchanged from r6) ----
template <int RS, int SW>
__device__ __forceinline__ u32x4 fragp(const U16* base, int row, int k, int lhi) {
    int slot = ((k >> 3) + lhi) ^ (row & SW);
    return *(const u32x4*)(base + row * RS + slot * 8);
}
template <int RS, int SW>
__device__ __forceinline__ void put16(U16* base, int row, int col, U16 v) {
    int slot = (col >> 3) ^ (row & SW);
    base[row * RS + slot * 8 + (col & 7)] = v;
}
template <int RS, int SW>
__device__ __forceinline__ void put64(U16* base, int row, int col0,
                                      U16 v0, U16 v1, U16 v2, U16 v3) {
    int slot = (col0 >> 3) ^ (row & SW);
    U32* p = (U32*)(base + row * RS + slot * 8 + (col0 & 7));
    p[0] = (U32)v0 | ((U32)v1 << 16);
    p[1] = (U32)v2 | ((U32)v3 << 16);
}

// ---- one-off weight conversion: fp32 -> hi/lo bf16 planes ----
__global__ __launch_bounds__(256) void convert_w(
    const float* __restrict__ Wq, const float* __restrict__ Wo,
    U16* __restrict__ qh, U16* __restrict__ ql,
    U16* __restrict__ oh, U16* __restrict__ ol)
{
    int i = blockIdx.x * 256 + threadIdx.x;
    if (i < 768 * 256) { U16 h, l; split_hl(Wq[i], h, l); qh[i] = h; ql[i] = l; }
    if (i < 256 * 256) { U16 h, l; split_hl(Wo[i], h, l); oh[i] = h; ol[i] = l; }
}

// ---- word level: 1 block = 1 sequence (L=64), 512 threads = 8 waves ----
__global__ __launch_bounds__(512, 4) void word_mfma(
    const float* __restrict__ x, const int* __restrict__ am,
    const U16* __restrict__ Wqh, const U16* __restrict__ Wql,
    const float* __restrict__ bqkv,
    const U16* __restrict__ Woh, const U16* __restrict__ Wol,
    const float* __restrict__ bo,
    U16* __restrict__ sent_hi, U16* __restrict__ sent_lo,
    float* __restrict__ smask)
{
    __shared__ __align__(16) U32 xc[64 * 64];   // x chunk (64 cols), 16 KB
    __shared__ __align__(16) U32 Qs[64 * 64];   // Q, later P
    __shared__ __align__(16) U32 Ks[64 * 64];   // K, later O
    __shared__ __align__(16) U32 Vt[64 * 64];   // V^T [d][m]
    __shared__ float msk[64];
    __shared__ float smsum;
    float* pool = (float*)xc;                   // aliases xc (dead at pool time)

    const int t = threadIdx.x;
    const int w = t >> 6, l = t & 63, l15 = l & 15, lhi = l >> 4;
    const int b = blockIdx.x;
    const float* xb = x + (size_t)b * 16384;

    if (t < 64) msk[t] = (float)am[b * 64 + t];

    const int srow = t >> 3, scol = t & 7;      // staging coords
    const int mtp = w >> 2, c0 = 3 * (w & 3);   // QKV: mt-pair + 3 col-groups
    const int sm = w & 3, dup = w >> 2;         // scores/PV roles
    const int smp = w & 1, ocq = w >> 1;        // out-proj roles

    f32x4 oacc[8];
    #pragma unroll
    for (int i = 0; i < 8; ++i) oacc[i] = f32x4{0.f, 0.f, 0.f, 0.f};

    for (int h = 0; h < 4; ++h) {
        // ---------------- QKV over 4 k-chunks of 64 ----------------
        float4 st0 = *(const float4*)(xb + srow * 256 + scol * 8);
        float4 st1 = *(const float4*)(xb + srow * 256 + scol * 8 + 4);
        f32x4 acc[6];
        #pragma unroll
        for (int i = 0; i < 6; ++i) acc[i] = f32x4{0.f, 0.f, 0.f, 0.f};

        for (int kc = 0; kc < 4; ++kc) {
            __syncthreads();                    // xc writable
            {
                int mm = srow & 15;
                u32x4 p0, p1;
                p0[0] = pack_hl(st0.x); p0[1] = pack_hl(st0.y);
                p0[2] = pack_hl(st0.z); p0[3] = pack_hl(st0.w);
                p1[0] = pack_hl(st1.x); p1[1] = pack_hl(st1.y);
                p1[2] = pack_hl(st1.z); p1[3] = pack_hl(st1.w);
                *(u32x4*)(xc + srow * 64 + ((scol * 2    ) ^ mm) * 4) = p0;
                *(u32x4*)(xc + srow * 64 + ((scol * 2 + 1) ^ mm) * 4) = p1;
            }
            __syncthreads();                    // xc readable
            if (kc < 3) {                       // T14: issue next-chunk loads early
                st0 = *(const float4*)(xb + srow * 256 + (kc + 1) * 64 + scol * 8);
                st1 = *(const float4*)(xb + srow * 256 + (kc + 1) * 64 + scol * 8 + 4);
            }
            #pragma unroll
            for (int ks = 0; ks < 2; ++ks) {
                u32x4 xh[2], xl[2];
                #pragma unroll
                for (int mi = 0; mi < 2; ++mi)
                    tile_frag(xc, (mtp * 2 + mi) * 16 + l15, ks * 8 + lhi * 2,
                              xh[mi], xl[mi]);
                const int kk = kc * 64 + ks * 32 + lhi * 8;
                #pragma unroll
                for (int j = 0; j < 3; ++j) {
                    const int c = c0 + j;
                    const size_t wr =
                        (size_t)((c >> 2) * 256 + h * 64 + (c & 3) * 16 + l15) * 256 + kk;
                    u32x4 wh = *(const u32x4*)(Wqh + wr);
                    u32x4 wl = *(const u32x4*)(Wql + wr);
                    acc[j]     = MFMA(xh[0], wh, acc[j]);
                    acc[j]     = MFMA(xh[0], wl, acc[j]);
                    acc[j]     = MFMA(xl[0], wh, acc[j]);
                    acc[3 + j] = MFMA(xh[1], wh, acc[3 + j]);
                    acc[3 + j] = MFMA(xh[1], wl, acc[3 + j]);
                    acc[3 + j] = MFMA(xl[1], wh, acc[3 + j]);
                }
            }
        }
        // ---------------- write Q/K/Vt tiles ----------------
        #pragma unroll
        for (int j = 0; j < 3; ++j) {
            const int c = c0 + j;
            const float bias = bqkv[(c >> 2) * 256 + h * 64 + (c & 3) * 16 + l15];
            #pragma unroll
            for (int mi = 0; mi < 2; ++mi) {
                const int mt = mtp * 2 + mi;
                f32x4 v = acc[mi * 3 + j];
                if (c < 8) {
                    U32* dst = (c < 4) ? Qs : Ks;
                    const int col = (c & 3) * 16 + l15;
                    #pragma unroll
                    for (int r = 0; r < 4; ++r)
                        tile_put(dst, mt * 16 + lhi * 4 + r, col, v[r] + bias);
                } else {
                    const int d = (c & 3) * 16 + l15;     // Vt row
                    u32x4 pv;
                    #pragma unroll
                    for (int r = 0; r < 4; ++r) pv[r] = pack_hl(v[r] + bias);
                    const int cs = (mt * 4 + lhi) ^ (d & 15);
                    *(u32x4*)(Vt + d * 64 + cs * 4) = pv;
                }
            }
        }
        __syncthreads();
        if (h == 0 && t == 0) {
            float s = 0.f;
            for (int i = 0; i < 64; ++i) s += msk[i];
            smsum = s;
        }
        // ---------------- scores + softmax + P (waves 0-3) ----------------
        if (dup == 0) {
            f32x4 sa[4];
            #pragma unroll
            for (int i = 0; i < 4; ++i) sa[i] = f32x4{0.f, 0.f, 0.f, 0.f};
            #pragma unroll
            for (int ks = 0; ks < 2; ++ks) {
                const int s0 = ks * 8 + lhi * 2;
                u32x4 qh, ql;
                tile_frag(Qs, sm * 16 + l15, s0, qh, ql);
                #pragma unroll
                for (int nt = 0; nt < 4; ++nt) {
                    u32x4 kh, kl;
                    tile_frag(Ks, nt * 16 + l15, s0, kh, kl);
                    sa[nt] = MFMA(qh, kh, sa[nt]);
                    sa[nt] = MFMA(qh, kl, sa[nt]);
                    sa[nt] = MFMA(ql, kh, sa[nt]);
                }
            }
            float sc[4][4];
            #pragma unroll
            for (int nt = 0; nt < 4; ++nt) {
                const float mterm = (1.0f - msk[nt * 16 + l15]) * -1e9f;
                #pragma unroll
                for (int r = 0; r < 4; ++r) sc[nt][r] = sa[nt][r] * 0.125f + mterm;
            }
            #pragma unroll
            for (int r = 0; r < 4; ++r) {
                float m = fmaxf(fmaxf(sc[0][r], sc[1][r]), fmaxf(sc[2][r], sc[3][r]));
                #pragma unroll
                for (int off = 1; off < 16; off <<= 1) m = fmaxf(m, __shfl_xor(m, off));
                float e0 = expf(sc[0][r] - m), e1 = expf(sc[1][r] - m);
                float e2 = expf(sc[2][r] - m), e3 = expf(sc[3][r] - m);
                float s = e0 + e1 + e2 + e3;
                #pragma unroll
                for (int off = 1; off < 16; off <<= 1) s += __shfl_xor(s, off);
                const float inv = 1.0f / s;
                sc[0][r] = e0 * inv; sc[1][r] = e1 * inv;
                sc[2][r] = e2 * inv; sc[3][r] = e3 * inv;
            }
            #pragma unroll
            for (int nt = 0; nt < 4; ++nt) {
                #pragma unroll
                for (int r = 0; r < 4; ++r)
                    tile_put(Qs, sm * 16 + lhi * 4 + r, nt * 16 + l15, sc[nt][r]);
            }
        }
        __syncthreads();
        // ---------------- PV (all 8 waves), O -> Ks ----------------
        {
            f32x4 pa[2];
            pa[0] = f32x4{0.f, 0.f, 0.f, 0.f};
            pa[1] = f32x4{0.f, 0.f, 0.f, 0.f};
            #pragma unroll
            for (int ks = 0; ks < 2; ++ks) {
                const int s0 = ks * 8 + lhi * 2;
                u32x4 ph, pl;
                tile_frag(Qs, sm * 16 + l15, s0, ph, pl);
                #pragma unroll
                for (int n2 = 0; n2 < 2; ++n2) {
                    u32x4 vh, vl;
                    tile_frag(Vt, (dup * 2 + n2) * 16 + l15, s0, vh, vl);
                    pa[n2] = MFMA(ph, vh, pa[n2]);
                    pa[n2] = MFMA(ph, vl, pa[n2]);
                    pa[n2] = MFMA(pl, vh, pa[n2]);
                }
            }
            #pragma unroll
            for (int n2 = 0; n2 < 2; ++n2) {
                #pragma unroll
                for (int r = 0; r < 4; ++r)
                    tile_put(Ks, sm * 16 + lhi * 4 + r,
                             (dup * 2 + n2) * 16 + l15, pa[n2][r]);
            }
        }
        __syncthreads();
        // ---------------- out-proj partial (oacc += O_h @ Wo_h^T) ----------------
        {
            #pragma unroll
            for (int ks = 0; ks < 2; ++ks) {
                const int s0 = ks * 8 + lhi * 2;
                u32x4 oh0, ol0, oh1, ol1;
                tile_frag(Ks, (smp * 2 + 0) * 16 + l15, s0, oh0, ol0);
                tile_frag(Ks, (smp * 2 + 1) * 16 + l15, s0, oh1, ol1);
                const int kk = h * 64 + ks * 32 + lhi * 8;
                #pragma unroll
                for (int j = 0; j < 4; ++j) {
                    const int oc = ocq * 64 + j * 16 + l15;
                    u32x4 wh = *(const u32x4*)(Woh + (size_t)oc * 256 + kk);
                    u32x4 wl = *(const u32x4*)(Wol + (size_t)oc * 256 + kk);
                    oacc[j]     = MFMA(oh0, wh, oacc[j]);
                    oacc[j]     = MFMA(oh0, wl, oacc[j]);
                    oacc[j]     = MFMA(ol0, wh, oacc[j]);
                    oacc[4 + j] = MFMA(oh1, wh, oacc[4 + j]);
                    oacc[4 + j] = MFMA(oh1, wl, oacc[4 + j]);
                    oacc[4 + j] = MFMA(ol1, wh, oacc[4 + j]);
                }
            }
        }
        // no barrier: next head's kc-loop barrier protects xc; tiles are only
        // rewritten after 2 more barriers.
    }

    // ---------------- masked mean pool ----------------
    {
        float colsum[4];
        #pragma unroll
        for (int j = 0; j < 4; ++j) {
            float s = 0.f;
            #pragma unroll
            for (int r = 0; r < 4; ++r) {
                s += msk[(smp * 2 + 0) * 16 + lhi * 4 + r] * oacc[j][r];
                s += msk[(smp * 2 + 1) * 16 + lhi * 4 + r] * oacc[4 + j][r];
            }
            s += __shfl_xor(s, 16);
            s += __shfl_xor(s, 32);
            colsum[j] = s;
        }
        __syncthreads();   // all waves past last xc read (h=3 QKV barriered)
        if (lhi == 0) {
            #pragma unroll
            for (int j = 0; j < 4; ++j)
                pool[smp * 256 + ocq * 64 + j * 16 + l15] = colsum[j];
        }
    }
    __syncthreads();
    if (t < 256) {
        float s = pool[t] + pool[256 + t];
        float m = smsum;
        float val = (s + bo[t] * m) / (m + 1e-10f);
        U16 vH, vL; split_hl(val, vH, vL);
        sent_hi[(size_t)b * 256 + t] = vH;
        sent_lo[(size_t)b * 256 + t] = vL;
    }
    if (t == 0) smask[b] = (smsum > 0.f) ? 1.f : 0.f;
}

// ---- levels 2/3: L in {16, 8}; 256 threads = 4 waves, wave = head ----
template <int L>
__global__ __launch_bounds__(256) void mha_small(
    const U16* __restrict__ xh, const U16* __restrict__ xl,  // [N*L][256]
    const float* __restrict__ mk,                            // [N*L]
    const U16* __restrict__ Wqh, const U16* __restrict__ Wql,
    const float* __restrict__ bqkv,
    const U16* __restrict__ Woh, const U16* __restrict__ Wol,
    const float* __restrict__ bo,
    float* __restrict__ out_f32, U16* __restrict__ out_hi, U16* __restrict__ out_lo,
    float* __restrict__ outmask)
{
    __shared__ __align__(16) U16 xs_h[16*256], xs_l[16*256];
    __shared__ __align__(16) U16 Qh_[16*256], Ql_[16*256];
    __shared__ __align__(16) U16 Kh_[16*256], Kl_[16*256];
    __shared__ __align__(16) U16 Vh_[256*32], Vl_[256*32];   // [d][j], j padded to 32
    __shared__ __align__(16) U16 Ph_[4][16*32], Pl_[4][16*32];
    __shared__ __align__(16) U16 Oh_[16*256], Ol_[16*256];
    __shared__ float msk[16];
    __shared__ float smsum;

    const int t = threadIdx.x;
    const int w = t >> 6, l = t & 63, l15 = l & 15, lhi = l >> 4;
    const int b = blockIdx.x;

    if (t < 16) msk[t] = (t < L) ? mk[b*L + t] : 0.f;

    #pragma unroll
    for (int i = 0; i < 2; ++i) {
        int c = i*256 + t;
        int row = c >> 5, c8 = c & 31;
        u32x4 hv = u32x4{0,0,0,0}, lv = u32x4{0,0,0,0};
        if (row < L) {
            hv = *(const u32x4*)(xh + ((size_t)b*L + row)*256 + c8*8);
            lv = *(const u32x4*)(xl + ((size_t)b*L + row)*256 + c8*8);
        }
        int slot = c8 ^ (row & 7);
        *(u32x4*)(xs_h + row*256 + slot*8) = hv;
        *(u32x4*)(xs_l + row*256 + slot*8) = lv;
    }
    #pragma unroll
    for (int i = 0; i < 4; ++i) {
        int c = i*256 + t;
        *(u32x4*)(Vh_ + c*8) = u32x4{0,0,0,0};
        *(u32x4*)(Vl_ + c*8) = u32x4{0,0,0,0};
    }
    *(u32x4*)(&Ph_[0][0] + t*8) = u32x4{0,0,0,0};
    *(u32x4*)(&Pl_[0][0] + t*8) = u32x4{0,0,0,0};
    __syncthreads();
    if (t == 0) { float s = 0.f; for (int i = 0; i < 16; ++i) s += msk[i]; smsum = s; }

    {
        f32x4 acc[12];
        #pragma unroll
        for (int i = 0; i < 12; ++i) acc[i] = f32x4{0.f,0.f,0.f,0.f};
        #pragma unroll 2
        for (int k0 = 0; k0 < 256; k0 += 32) {
            u32x4 ah = fragp<256,7>(xs_h, l15, k0, lhi);
            u32x4 al = fragp<256,7>(xs_l, l15, k0, lhi);
            #pragma unroll
            for (int j = 0; j < 12; ++j) {
                int u = w*12 + j;
                u32x4 wh = *(const u32x4*)(Wqh + (size_t)(u*16 + l15)*256 + k0 + lhi*8);
                u32x4 wl = *(const u32x4*)(Wql + (size_t)(u*16 + l15)*256 + k0 + lhi*8);
                acc[j] = MFMA(ah, wh, acc[j]);
                acc[j] = MFMA(ah, wl, acc[j]);
                acc[j] = MFMA(al, wh, acc[j]);
            }
        }
        #pragma unroll
        for (int j = 0; j < 12; ++j) {
            int u = w*12 + j;
            int mat = u >> 4, cg = u & 15;
            float bias = bqkv[u*16 + l15];
            if (mat < 2) {
                U16* dh = (mat == 0) ? Qh_ : Kh_;
                U16* dl = (mat == 0) ? Ql_ : Kl_;
                #pragma unroll
                for (int r = 0; r < 4; ++r) {
                    U16 vH, vL; split_hl(acc[j][r] + bias, vH, vL);
                    put16<256,7>(dh, lhi*4 + r, cg*16 + l15, vH);
                    put16<256,7>(dl, lhi*4 + r, cg*16 + l15, vL);
                }
            } else {
                U16 h4[4], l4[4];
                #pragma unroll
                for (int r = 0; r < 4; ++r) split_hl(acc[j][r] + bias, h4[r], l4[r]);
                put64<32,3>(Vh_, cg*16 + l15, lhi*4, h4[0],h4[1],h4[2],h4[3]);
                put64<32,3>(Vl_, cg*16 + l15, lhi*4, l4[0],l4[1],l4[2],l4[3]);
            }
        }
    }
    __syncthreads();

    {
        const int h = w;
        f32x4 sa = f32x4{0.f,0.f,0.f,0.f};
        #pragma unroll
        for (int k0 = 0; k0 < 64; k0 += 32) {
            u32x4 qh = fragp<256,7>(Qh_, l15, h*64 + k0, lhi);
            u32x4 ql = fragp<256,7>(Ql_, l15, h*64 + k0, lhi);
            u32x4 kh = fragp<256,7>(Kh_, l15, h*64 + k0, lhi);
            u32x4 kl = fragp<256,7>(Kl_, l15, h*64 + k0, lhi);
            sa = MFMA(qh, kh, sa);
            sa = MFMA(qh, kl, sa);
            sa = MFMA(ql, kh, sa);
        }
        float sc[4];
        float mterm = (1.0f - msk[l15]) * -1e9f;
        #pragma unroll
        for (int r = 0; r < 4; ++r) sc[r] = sa[r] * 0.125f + mterm;
        #pragma unroll
        for (int r = 0; r < 4; ++r) {
            float m = sc[r];
            #pragma unroll
            for (int off = 1; off < 16; off <<= 1) m = fmaxf(m, __shfl_xor(m, off));
            float e = expf(sc[r] - m);
            float s = e;
            #pragma unroll
            for (int off = 1; off < 16; off <<= 1) s += __shfl_xor(s, off);
            sc[r] = e / s;
        }
        #pragma unroll
        for (int r = 0; r < 4; ++r) {
            U16 vH, vL; split_hl(sc[r], vH, vL);
            put16<32,3>(&Ph_[h][0], lhi*4 + r, l15, vH);
            put16<32,3>(&Pl_[h][0], lhi*4 + r, l15, vL);
        }
        f32x4 pa[4];
        #pragma unroll
        for (int i = 0; i < 4; ++i) pa[i] = f32x4{0.f,0.f,0.f,0.f};
        {
            u32x4 ph = fragp<32,3>(&Ph_[h][0], l15, 0, lhi);
            u32x4 pl = fragp<32,3>(&Pl_[h][0], l15, 0, lhi);
            #pragma unroll
            for (int ntl = 0; ntl < 4; ++ntl) {
                u32x4 vh = fragp<32,3>(Vh_, h*64 + ntl*16 + l15, 0, lhi);
                u32x4 vl = fragp<32,3>(Vl_, h*64 + ntl*16 + l15, 0, lhi);
                pa[ntl] = MFMA(ph, vh, pa[ntl]);
                pa[ntl] = MFMA(ph, vl, pa[ntl]);
                pa[ntl] = MFMA(pl, vh, pa[ntl]);
            }
        }
        #pragma unroll
        for (int ntl = 0; ntl < 4; ++ntl) {
            #pragma unroll
            for (int r = 0; r < 4; ++r) {
                U16 vH, vL; split_hl(pa[ntl][r], vH, vL);
                put16<256,7>(Oh_, lhi*4 + r, h*64 + ntl*16 + l15, vH);
                put16<256,7>(Ol_, lhi*4 + r, h*64 + ntl*16 + l15, vL);
            }
        }
    }
    __syncthreads();

    {
        f32x4 acc4[4];
        #pragma unroll
        for (int i = 0; i < 4; ++i) acc4[i] = f32x4{0.f,0.f,0.f,0.f};
        #pragma unroll 2
        for (int k0 = 0; k0 < 256; k0 += 32) {
            u32x4 oh = fragp<256,7>(Oh_, l15, k0, lhi);
            u32x4 ol = fragp<256,7>(Ol_, l15, k0, lhi);
            #pragma unroll
            for (int j = 0; j < 4; ++j) {
                int oc = w*64 + j*16 + l15;
                u32x4 wh = *(const u32x4*)(Woh + (size_t)oc*256 + k0 + lhi*8);
                u32x4 wl = *(const u32x4*)(Wol + (size_t)oc*256 + k0 + lhi*8);
                acc4[j] = MFMA(oh, wh, acc4[j]);
                acc4[j] = MFMA(oh, wl, acc4[j]);
                acc4[j] = MFMA(ol, wh, acc4[j]);
            }
        }
        float msum = smsum;
        #pragma unroll
        for (int j = 0; j < 4; ++j) {
            float s = 0.f;
            #pragma unroll
            for (int r = 0; r < 4; ++r) s += msk[lhi*4 + r] * acc4[j][r];
            s += __shfl_xor(s, 16);
            s += __shfl_xor(s, 32);
            if (lhi == 0) {
                int col = w*64 + j*16 + l15;
                float val = (s + bo[col] * msum) / (msum + 1e-10f);
                if (out_f32) out_f32[(size_t)b*256 + col] = val;
                if (out_hi) {
                    U16 vH, vL; split_hl(val, vH, vL);
                    out_hi[(size_t)b*256 + col] = vH;
                    out_lo[(size_t)b*256 + col] = vL;
                }
            }
        }
    }
    if (t == 0 && outmask) outmask[b] = (smsum > 0.f) ? 1.f : 0.f;
}

extern "C" void kernel_launch(void* const* d_in, const int* in_sizes, int n_in,
                              void* d_out, int out_size, void* d_ws, size_t ws_size,
                              hipStream_t stream) {
    (void)in_sizes; (void)n_in; (void)out_size; (void)ws_size;
    const float* we  = (const float*)d_in[0];
    const int*   am  = (const int*)d_in[1];
    const float* wW  = (const float*)d_in[2];
    const float* wb  = (const float*)d_in[3];
    const float* wO  = (const float*)d_in[4];
    const float* wob = (const float*)d_in[5];
    const float* sW  = (const float*)d_in[6];
    const float* sb  = (const float*)d_in[7];
    const float* sO  = (const float*)d_in[8];
    const float* sob = (const float*)d_in[9];
    const float* cW  = (const float*)d_in[10];
    const float* cb  = (const float*)d_in[11];
    const float* cO  = (const float*)d_in[12];
    const float* cob = (const float*)d_in[13];

    U16* p = (U16*)d_ws;
    U16* sent_hi = p; p += 2048*256;
    U16* sent_lo = p; p += 2048*256;
    U16* sect_hi = p; p += 128*256;
    U16* sect_lo = p; p += 128*256;
    U16* w1qh = p; p += 768*256;  U16* w1ql = p; p += 768*256;
    U16* w1oh = p; p += 256*256;  U16* w1ol = p; p += 256*256;
    U16* w2qh = p; p += 768*256;  U16* w2ql = p; p += 768*256;
    U16* w2oh = p; p += 256*256;  U16* w2ol = p; p += 256*256;
    U16* w3qh = p; p += 768*256;  U16* w3ql = p; p += 768*256;
    U16* w3oh = p; p += 256*256;  U16* w3ol = p; p += 256*256;
    float* smaskb = (float*)p;
    float* cmaskb = smaskb + 2048;

    convert_w<<<768, 256, 0, stream>>>(wW, wO, w1qh, w1ql, w1oh, w1ol);
    convert_w<<<768, 256, 0, stream>>>(sW, sO, w2qh, w2ql, w2oh, w2ol);
    convert_w<<<768, 256, 0, stream>>>(cW, cO, w3qh, w3ql, w3oh, w3ol);
    word_mfma<<<2048, 512, 0, stream>>>(we, am, w1qh, w1ql, wb, w1oh, w1ol, wob,
                                        sent_hi, sent_lo, smaskb);
    mha_small<16><<<128, 256, 0, stream>>>(sent_hi, sent_lo, smaskb,
                                           w2qh, w2ql, sb, w2oh, w2ol, sob,
                                           nullptr, sect_hi, sect_lo, cmaskb);
    mha_small<8><<<16, 256, 0, stream>>>(sect_hi, sect_lo, cmaskb,
                                         w3qh, w3ql, cb, w3oh, w3ol, cob,
                                         (float*)d_out, nullptr, nullptr, nullptr);
}

// Round 8
// 918.617 us; speedup vs baseline: 5.2779x; 1.0012x over previous
//
#include <hip/hip_runtime.h>
#include <hip/hip_bf16.h>

// Hierarchical attention, 3 levels, all GEMM phases on split-bf16 MFMA:
// value = hi + lo (two bf16); every product = 3x mfma_f32_16x16x32_bf16
// (hi*hi + hi*lo + lo*hi), ~fp32 precision at matrix-core rate.
// Word level: 256 thr/block (4 waves), launch_bounds(256,2) -> VGPR cap 256
// (NO spills - r7's (512,4) cap of 128 caused 567 MB scratch traffic).
// LDS tiles: packed u32 (hi<<16|lo), 256B rows, XOR-16 swizzle.
// Wave-ownership: scores->PV->outproj barrier-free (own-row P/O, O in xc).

typedef short bf16x8 __attribute__((ext_vector_type(8)));
typedef float f32x4 __attribute__((ext_vector_type(4)));
typedef unsigned int u32x4 __attribute__((ext_vector_type(4)));
typedef unsigned short U16;
typedef unsigned int U32;

__device__ __forceinline__ U32 bf16_rne(float f) {
    U32 u = __builtin_bit_cast(U32, f);
    return (u + 0x7FFFu + ((u >> 16) & 1u)) >> 16;
}
__device__ __forceinline__ void split_hl(float f, U16& h, U16& l) {
    U32 hu = bf16_rne(f);
    float hf = __builtin_bit_cast(float, hu << 16);
    h = (U16)hu;
    l = (U16)bf16_rne(f - hf);
}
__device__ __forceinline__ U32 pack_hl(float f) {
    U32 hu = bf16_rne(f);
    float hf = __builtin_bit_cast(float, hu << 16);
    U32 lo = bf16_rne(f - hf);
    return (hu << 16) | (lo & 0xFFFFu);
}

__device__ __forceinline__ void unpack8(u32x4 a, u32x4 b, u32x4& hi, u32x4& lo) {
    hi[0] = __builtin_amdgcn_perm(a[1], a[0], 0x07060302u);
    hi[1] = __builtin_amdgcn_perm(a[3], a[2], 0x07060302u);
    hi[2] = __builtin_amdgcn_perm(b[1], b[0], 0x07060302u);
    hi[3] = __builtin_amdgcn_perm(b[3], b[2], 0x07060302u);
    lo[0] = __builtin_amdgcn_perm(a[1], a[0], 0x05040100u);
    lo[1] = __builtin_amdgcn_perm(a[3], a[2], 0x05040100u);
    lo[2] = __builtin_amdgcn_perm(b[1], b[0], 0x05040100u);
    lo[3] = __builtin_amdgcn_perm(b[3], b[2], 0x05040100u);
}

#define MFMA(A, B, C) __builtin_amdgcn_mfma_f32_16x16x32_bf16( \
    __builtin_bit_cast(bf16x8, A), __builtin_bit_cast(bf16x8, B), C, 0, 0, 0)

// Packed-u32 tile (row stride 64 u32 = 256 B, 16 slots of 16B, XOR-16 swizzle).
__device__ __forceinline__ void tile_frag(const U32* tile, int row, int s0,
                                          u32x4& hi, u32x4& lo) {
    int m = row & 15;
    u32x4 a = *(const u32x4*)(tile + row * 64 + ((s0    ) ^ m) * 4);
    u32x4 b = *(const u32x4*)(tile + row * 64 + ((s0 + 1) ^ m) * 4);
    unpack8(a, b, hi, lo);
}
__device__ __forceinline__ void tile_put(U32* tile, int row, int col, float v) {
    tile[row * 64 + (((col >> 2) ^ (row & 15))) * 4 + (col & 3)] = pack_hl(v);
}

// ---- hi/lo plane helpers for mha_small ----
template <int RS, int SW>
__device__ __forceinline__ u32x4 fragp(const U16* base, int row, int k, int lhi) {
    int slot = ((k >> 3) + lhi) ^ (row & SW);
    return *(const u32x4*)(base + row * RS + slot * 8);
}
template <int RS, int SW>
__device__ __forceinline__ void put16(U16* base, int row, int col, U16 v) {
    int slot = (col >> 3) ^ (row & SW);
    base[row * RS + slot * 8 + (col & 7)] = v;
}
template <int RS, int SW>
__device__ __forceinline__ void put64(U16* base, int row, int col0,
                                      U16 v0, U16 v1, U16 v2, U16 v3) {
    int slot = (col0 >> 3) ^ (row & SW);
    U32* p = (U32*)(base + row * RS + slot * 8 + (col0 & 7));
    p[0] = (U32)v0 | ((U32)v1 << 16);
    p[1] = (U32)v2 | ((U32)v3 << 16);
}

__global__ __launch_bounds__(256) void convert_w(
    const float* __restrict__ Wq, const float* __restrict__ Wo,
    U16* __restrict__ qh, U16* __restrict__ ql,
    U16* __restrict__ oh, U16* __restrict__ ol)
{
    int i = blockIdx.x * 256 + threadIdx.x;
    if (i < 768 * 256) { U16 h, l; split_hl(Wq[i], h, l); qh[i] = h; ql[i] = l; }
    if (i < 256 * 256) { U16 h, l; split_hl(Wo[i], h, l); oh[i] = h; ol[i] = l; }
}

// ---- word level: 1 block = 1 sequence (L=64), 256 threads = 4 waves ----
__global__ __launch_bounds__(256, 2) void word_mfma(
    const float* __restrict__ x, const int* __restrict__ am,
    const U16* __restrict__ Wqh, const U16* __restrict__ Wql,
    const float* __restrict__ bqkv,
    const U16* __restrict__ Woh, const U16* __restrict__ Wol,
    const float* __restrict__ bo,
    U16* __restrict__ sent_hi, U16* __restrict__ sent_lo,
    float* __restrict__ smask)
{
    __shared__ __align__(16) U32 xc[64 * 64];   // x chunk; later O tile; later pool
    __shared__ __align__(16) U32 Qs[64 * 64];   // Q, later P
    __shared__ __align__(16) U32 Ks[64 * 64];   // K
    __shared__ __align__(16) U32 Vt[64 * 64];   // V^T [d][m]
    __shared__ float msk[64];
    __shared__ float smsum;

    const int t = threadIdx.x;
    const int w = t >> 6, l = t & 63, l15 = l & 15, lhi = l >> 4;
    const int b = blockIdx.x;
    const float* xb = x + (size_t)b * 16384;

    if (t < 64) msk[t] = (float)am[b * 64 + t];

    // staging coords: 512 units of 8 floats; thread t handles units t, t+256
    const int r0 = t >> 3, c8 = t & 7;          // unit t:     row r0,      cols c8*8..
    const int r1 = r0 + 32;                     // unit t+256: row r0+32

    f32x4 oacc[16];
    #pragma unroll
    for (int i = 0; i < 16; ++i) oacc[i] = f32x4{0.f, 0.f, 0.f, 0.f};

    for (int h = 0; h < 4; ++h) {
        // ---------------- QKV over 4 k-chunks of 64 ----------------
        float4 s00 = *(const float4*)(xb + r0 * 256 + c8 * 8);
        float4 s01 = *(const float4*)(xb + r0 * 256 + c8 * 8 + 4);
        float4 s10 = *(const float4*)(xb + r1 * 256 + c8 * 8);
        float4 s11 = *(const float4*)(xb + r1 * 256 + c8 * 8 + 4);
        f32x4 acc[3][4];
        #pragma unroll
        for (int j = 0; j < 3; ++j)
            #pragma unroll
            for (int mt = 0; mt < 4; ++mt) acc[j][mt] = f32x4{0.f, 0.f, 0.f, 0.f};

        for (int kc = 0; kc < 4; ++kc) {
            __syncthreads();                    // xc writable (prev readers done)
            {
                u32x4 p0, p1;
                p0[0] = pack_hl(s00.x); p0[1] = pack_hl(s00.y);
                p0[2] = pack_hl(s00.z); p0[3] = pack_hl(s00.w);
                p1[0] = pack_hl(s01.x); p1[1] = pack_hl(s01.y);
                p1[2] = pack_hl(s01.z); p1[3] = pack_hl(s01.w);
                int mm = r0 & 15;
                *(u32x4*)(xc + r0 * 64 + ((c8 * 2    ) ^ mm) * 4) = p0;
                *(u32x4*)(xc + r0 * 64 + ((c8 * 2 + 1) ^ mm) * 4) = p1;
                p0[0] = pack_hl(s10.x); p0[1] = pack_hl(s10.y);
                p0[2] = pack_hl(s10.z); p0[3] = pack_hl(s10.w);
                p1[0] = pack_hl(s11.x); p1[1] = pack_hl(s11.y);
                p1[2] = pack_hl(s11.z); p1[3] = pack_hl(s11.w);
                mm = r1 & 15;
                *(u32x4*)(xc + r1 * 64 + ((c8 * 2    ) ^ mm) * 4) = p0;
                *(u32x4*)(xc + r1 * 64 + ((c8 * 2 + 1) ^ mm) * 4) = p1;
            }
            __syncthreads();                    // xc readable
            if (kc < 3) {                       // prefetch next chunk (T14)
                s00 = *(const float4*)(xb + r0 * 256 + (kc + 1) * 64 + c8 * 8);
                s01 = *(const float4*)(xb + r0 * 256 + (kc + 1) * 64 + c8 * 8 + 4);
                s10 = *(const float4*)(xb + r1 * 256 + (kc + 1) * 64 + c8 * 8);
                s11 = *(const float4*)(xb + r1 * 256 + (kc + 1) * 64 + c8 * 8 + 4);
            }
            #pragma unroll
            for (int ks = 0; ks < 2; ++ks) {
                const int s0 = ks * 8 + lhi * 2;
                u32x4 xh[4], xl[4];
                #pragma unroll
                for (int mt = 0; mt < 4; ++mt)
                    tile_frag(xc, mt * 16 + l15, s0, xh[mt], xl[mt]);
                const int kk = kc * 64 + ks * 32 + lhi * 8;
                #pragma unroll
                for (int j = 0; j < 3; ++j) {
                    const size_t wr =
                        (size_t)(j * 256 + h * 64 + w * 16 + l15) * 256 + kk;
                    u32x4 wh = *(const u32x4*)(Wqh + wr);
                    u32x4 wl = *(const u32x4*)(Wql + wr);
                    #pragma unroll
                    for (int mt = 0; mt < 4; ++mt) {
                        acc[j][mt] = MFMA(xh[mt], wh, acc[j][mt]);
                        acc[j][mt] = MFMA(xh[mt], wl, acc[j][mt]);
                        acc[j][mt] = MFMA(xl[mt], wh, acc[j][mt]);
                    }
                }
            }
        }
        // ---------------- write Q / K / Vt tiles ----------------
        {
            const float bQ = bqkv[          h * 64 + w * 16 + l15];
            const float bK = bqkv[256     + h * 64 + w * 16 + l15];
            const float bV = bqkv[512     + h * 64 + w * 16 + l15];
            #pragma unroll
            for (int mt = 0; mt < 4; ++mt) {
                #pragma unroll
                for (int r = 0; r < 4; ++r) {
                    tile_put(Qs, mt * 16 + lhi * 4 + r, w * 16 + l15, acc[0][mt][r] + bQ);
                    tile_put(Ks, mt * 16 + lhi * 4 + r, w * 16 + l15, acc[1][mt][r] + bK);
                }
                const int d = w * 16 + l15;
                u32x4 pv;
                #pragma unroll
                for (int r = 0; r < 4; ++r) pv[r] = pack_hl(acc[2][mt][r] + bV);
                const int cs = (mt * 4 + lhi) ^ (d & 15);
                *(u32x4*)(Vt + d * 64 + cs * 4) = pv;
            }
        }
        __syncthreads();   // tiles ready for all waves

        // ------- scores + softmax + P (wave w owns row-tile w) -------
        {
            f32x4 sa[4];
            #pragma unroll
            for (int i = 0; i < 4; ++i) sa[i] = f32x4{0.f, 0.f, 0.f, 0.f};
            #pragma unroll
            for (int ks = 0; ks < 2; ++ks) {
                const int s0 = ks * 8 + lhi * 2;
                u32x4 qh, ql;
                tile_frag(Qs, w * 16 + l15, s0, qh, ql);
                #pragma unroll
                for (int nt = 0; nt < 4; ++nt) {
                    u32x4 kh, kl;
                    tile_frag(Ks, nt * 16 + l15, s0, kh, kl);
                    sa[nt] = MFMA(qh, kh, sa[nt]);
                    sa[nt] = MFMA(qh, kl, sa[nt]);
                    sa[nt] = MFMA(ql, kh, sa[nt]);
                }
            }
            float sc[4][4];
            #pragma unroll
            for (int nt = 0; nt < 4; ++nt) {
                const float mterm = (1.0f - msk[nt * 16 + l15]) * -1e9f;
                #pragma unroll
                for (int r = 0; r < 4; ++r) sc[nt][r] = sa[nt][r] * 0.125f + mterm;
            }
            #pragma unroll
            for (int r = 0; r < 4; ++r) {
                float m = fmaxf(fmaxf(sc[0][r], sc[1][r]), fmaxf(sc[2][r], sc[3][r]));
                #pragma unroll
                for (int off = 1; off < 16; off <<= 1) m = fmaxf(m, __shfl_xor(m, off));
                float e0 = expf(sc[0][r] - m), e1 = expf(sc[1][r] - m);
                float e2 = expf(sc[2][r] - m), e3 = expf(sc[3][r] - m);
                float s = e0 + e1 + e2 + e3;
                #pragma unroll
                for (int off = 1; off < 16; off <<= 1) s += __shfl_xor(s, off);
                const float inv = 1.0f / s;
                sc[0][r] = e0 * inv; sc[1][r] = e1 * inv;
                sc[2][r] = e2 * inv; sc[3][r] = e3 * inv;
            }
            // P -> Qs own rows only (no other wave reads these rows)
            #pragma unroll
            for (int nt = 0; nt < 4; ++nt)
                #pragma unroll
                for (int r = 0; r < 4; ++r)
                    tile_put(Qs, w * 16 + lhi * 4 + r, nt * 16 + l15, sc[nt][r]);
        }
        // ------- PV (no barrier: P own rows, Vt barriered) ; O -> xc -------
        {
            f32x4 pa[4];
            #pragma unroll
            for (int i = 0; i < 4; ++i) pa[i] = f32x4{0.f, 0.f, 0.f, 0.f};
            #pragma unroll
            for (int ks = 0; ks < 2; ++ks) {
                const int s0 = ks * 8 + lhi * 2;
                u32x4 ph, pl;
                tile_frag(Qs, w * 16 + l15, s0, ph, pl);
                #pragma unroll
                for (int nt = 0; nt < 4; ++nt) {
                    u32x4 vh, vl;
                    tile_frag(Vt, nt * 16 + l15, s0, vh, vl);
                    pa[nt] = MFMA(ph, vh, pa[nt]);
                    pa[nt] = MFMA(ph, vl, pa[nt]);
                    pa[nt] = MFMA(pl, vh, pa[nt]);
                }
            }
            #pragma unroll
            for (int nt = 0; nt < 4; ++nt)
                #pragma unroll
                for (int r = 0; r < 4; ++r)
                    tile_put(xc, w * 16 + lhi * 4 + r, nt * 16 + l15, pa[nt][r]);
        }
        // ------- out-proj partial (no barrier: O own rows in xc) -------
        {
            #pragma unroll
            for (int ks = 0; ks < 2; ++ks) {
                const int s0 = ks * 8 + lhi * 2;
                u32x4 oh, ol;
                tile_frag(xc, w * 16 + l15, s0, oh, ol);
                const int kk = h * 64 + ks * 32 + lhi * 8;
                #pragma unroll
                for (int j = 0; j < 16; ++j) {
                    const size_t wr = (size_t)(j * 16 + l15) * 256 + kk;
                    u32x4 wh = *(const u32x4*)(Woh + wr);
                    u32x4 wl = *(const u32x4*)(Wol + wr);
                    oacc[j] = MFMA(oh, wh, oacc[j]);
                    oacc[j] = MFMA(oh, wl, oacc[j]);
                    oacc[j] = MFMA(ol, wh, oacc[j]);
                }
            }
        }
        // next head's kc-loop barrier orders xc overwrite after outproj reads
    }

    __syncthreads();   // all outproj xc reads done; xc becomes pool buffer
    if (t == 0) { float s = 0.f; for (int i = 0; i < 64; ++i) s += msk[i]; smsum = s; }
    float* pool = (float*)xc;   // [4][256]
    {
        #pragma unroll
        for (int j = 0; j < 16; ++j) {
            float s = 0.f;
            #pragma unroll
            for (int r = 0; r < 4; ++r) s += msk[w * 16 + lhi * 4 + r] * oacc[j][r];
            s += __shfl_xor(s, 16);
            s += __shfl_xor(s, 32);
            if (lhi == 0) pool[w * 256 + j * 16 + l15] = s;
        }
    }
    __syncthreads();
    {
        float s = pool[t] + pool[256 + t] + pool[512 + t] + pool[768 + t];
        float m = smsum;
        float val = (s + bo[t] * m) / (m + 1e-10f);
        U16 vH, vL; split_hl(val, vH, vL);
        sent_hi[(size_t)b * 256 + t] = vH;
        sent_lo[(size_t)b * 256 + t] = vL;
    }
    if (t == 0) smask[b] = (smsum > 0.f) ? 1.f : 0.f;
}

// ---- levels 2/3: L in {16, 8}; 256 threads = 4 waves, wave = head ----
template <int L>
__global__ __launch_bounds__(256) void mha_small(
    const U16* __restrict__ xh, const U16* __restrict__ xl,
    const float* __restrict__ mk,
    const U16* __restrict__ Wqh, const U16* __restrict__ Wql,
    const float* __restrict__ bqkv,
    const U16* __restrict__ Woh, const U16* __restrict__ Wol,
    const float* __restrict__ bo,
    float* __restrict__ out_f32, U16* __restrict__ out_hi, U16* __restrict__ out_lo,
    float* __restrict__ outmask)
{
    __shared__ __align__(16) U16 xs_h[16*256], xs_l[16*256];
    __shared__ __align__(16) U16 Qh_[16*256], Ql_[16*256];
    __shared__ __align__(16) U16 Kh_[16*256], Kl_[16*256];
    __shared__ __align__(16) U16 Vh_[256*32], Vl_[256*32];
    __shared__ __align__(16) U16 Ph_[4][16*32], Pl_[4][16*32];
    __shared__ __align__(16) U16 Oh_[16*256], Ol_[16*256];
    __shared__ float msk[16];
    __shared__ float smsum;

    const int t = threadIdx.x;
    const int w = t >> 6, l = t & 63, l15 = l & 15, lhi = l >> 4;
    const int b = blockIdx.x;

    if (t < 16) msk[t] = (t < L) ? mk[b*L + t] : 0.f;

    #pragma unroll
    for (int i = 0; i < 2; ++i) {
        int c = i*256 + t;
        int row = c >> 5, c8 = c & 31;
        u32x4 hv = u32x4{0,0,0,0}, lv = u32x4{0,0,0,0};
        if (row < L) {
            hv = *(const u32x4*)(xh + ((size_t)b*L + row)*256 + c8*8);
            lv = *(const u32x4*)(xl + ((size_t)b*L + row)*256 + c8*8);
        }
        int slot = c8 ^ (row & 7);
        *(u32x4*)(xs_h + row*256 + slot*8) = hv;
        *(u32x4*)(xs_l + row*256 + slot*8) = lv;
    }
    #pragma unroll
    for (int i = 0; i < 4; ++i) {
        int c = i*256 + t;
        *(u32x4*)(Vh_ + c*8) = u32x4{0,0,0,0};
        *(u32x4*)(Vl_ + c*8) = u32x4{0,0,0,0};
    }
    *(u32x4*)(&Ph_[0][0] + t*8) = u32x4{0,0,0,0};
    *(u32x4*)(&Pl_[0][0] + t*8) = u32x4{0,0,0,0};
    __syncthreads();
    if (t == 0) { float s = 0.f; for (int i = 0; i < 16; ++i) s += msk[i]; smsum = s; }

    {
        f32x4 acc[12];
        #pragma unroll
        for (int i = 0; i < 12; ++i) acc[i] = f32x4{0.f,0.f,0.f,0.f};
        #pragma unroll 2
        for (int k0 = 0; k0 < 256; k0 += 32) {
            u32x4 ah = fragp<256,7>(xs_h, l15, k0, lhi);
            u32x4 al = fragp<256,7>(xs_l, l15, k0, lhi);
            #pragma unroll
            for (int j = 0; j < 12; ++j) {
                int u = w*12 + j;
                u32x4 wh = *(const u32x4*)(Wqh + (size_t)(u*16 + l15)*256 + k0 + lhi*8);
                u32x4 wl = *(const u32x4*)(Wql + (size_t)(u*16 + l15)*256 + k0 + lhi*8);
                acc[j] = MFMA(ah, wh, acc[j]);
                acc[j] = MFMA(ah, wl, acc[j]);
                acc[j] = MFMA(al, wh, acc[j]);
            }
        }
        #pragma unroll
        for (int j = 0; j < 12; ++j) {
            int u = w*12 + j;
            int mat = u >> 4, cg = u & 15;
            float bias = bqkv[u*16 + l15];
            if (mat < 2) {
                U16* dh = (mat == 0) ? Qh_ : Kh_;
                U16* dl = (mat == 0) ? Ql_ : Kl_;
                #pragma unroll
                for (int r = 0; r < 4; ++r) {
                    U16 vH, vL; split_hl(acc[j][r] + bias, vH, vL);
                    put16<256,7>(dh, lhi*4 + r, cg*16 + l15, vH);
                    put16<256,7>(dl, lhi*4 + r, cg*16 + l15, vL);
                }
            } else {
                U16 h4[4], l4[4];
                #pragma unroll
                for (int r = 0; r < 4; ++r) split_hl(acc[j][r] + bias, h4[r], l4[r]);
                put64<32,3>(Vh_, cg*16 + l15, lhi*4, h4[0],h4[1],h4[2],h4[3]);
                put64<32,3>(Vl_, cg*16 + l15, lhi*4, l4[0],l4[1],l4[2],l4[3]);
            }
        }
    }
    __syncthreads();

    {
        const int h = w;
        f32x4 sa = f32x4{0.f,0.f,0.f,0.f};
        #pragma unroll
        for (int k0 = 0; k0 < 64; k0 += 32) {
            u32x4 qh = fragp<256,7>(Qh_, l15, h*64 + k0, lhi);
            u32x4 ql = fragp<256,7>(Ql_, l15, h*64 + k0, lhi);
            u32x4 kh = fragp<256,7>(Kh_, l15, h*64 + k0, lhi);
            u32x4 kl = fragp<256,7>(Kl_, l15, h*64 + k0, lhi);
            sa = MFMA(qh, kh, sa);
            sa = MFMA(qh, kl, sa);
            sa = MFMA(ql, kh, sa);
        }
        float sc[4];
        float mterm = (1.0f - msk[l15]) * -1e9f;
        #pragma unroll
        for (int r = 0; r < 4; ++r) sc[r] = sa[r] * 0.125f + mterm;
        #pragma unroll
        for (int r = 0; r < 4; ++r) {
            float m = sc[r];
            #pragma unroll
            for (int off = 1; off < 16; off <<= 1) m = fmaxf(m, __shfl_xor(m, off));
            float e = expf(sc[r] - m);
            float s = e;
            #pragma unroll
            for (int off = 1; off < 16; off <<= 1) s += __shfl_xor(s, off);
            sc[r] = e / s;
        }
        #pragma unroll
        for (int r = 0; r < 4; ++r) {
            U16 vH, vL; split_hl(sc[r], vH, vL);
            put16<32,3>(&Ph_[h][0], lhi*4 + r, l15, vH);
            put16<32,3>(&Pl_[h][0], lhi*4 + r, l15, vL);
        }
        f32x4 pa[4];
        #pragma unroll
        for (int i = 0; i < 4; ++i) pa[i] = f32x4{0.f,0.f,0.f,0.f};
        {
            u32x4 ph = fragp<32,3>(&Ph_[h][0], l15, 0, lhi);
            u32x4 pl = fragp<32,3>(&Pl_[h][0], l15, 0, lhi);
            #pragma unroll
            for (int ntl = 0; ntl < 4; ++ntl) {
                u32x4 vh = fragp<32,3>(Vh_, h*64 + ntl*16 + l15, 0, lhi);
                u32x4 vl = fragp<32,3>(Vl_, h*64 + ntl*16 + l15, 0, lhi);
                pa[ntl] = MFMA(ph, vh, pa[ntl]);
                pa[ntl] = MFMA(ph, vl, pa[ntl]);
                pa[ntl] = MFMA(pl, vh, pa[ntl]);
            }
        }
        #pragma unroll
        for (int ntl = 0; ntl < 4; ++ntl) {
            #pragma unroll
            for (int r = 0; r < 4; ++r) {
                U16 vH, vL; split_hl(pa[ntl][r], vH, vL);
                put16<256,7>(Oh_, lhi*4 + r, h*64 + ntl*16 + l15, vH);
                put16<256,7>(Ol_, lhi*4 + r, h*64 + ntl*16 + l15, vL);
            }
        }
    }
    __syncthreads();

    {
        f32x4 acc4[4];
        #pragma unroll
        for (int i = 0; i < 4; ++i) acc4[i] = f32x4{0.f,0.f,0.f,0.f};
        #pragma unroll 2
        for (int k0 = 0; k0 < 256; k0 += 32) {
            u32x4 oh = fragp<256,7>(Oh_, l15, k0, lhi);
            u32x4 ol = fragp<256,7>(Ol_, l15, k0, lhi);
            #pragma unroll
            for (int j = 0; j < 4; ++j) {
                int oc = w*64 + j*16 + l15;
                u32x4 wh = *(const u32x4*)(Woh + (size_t)oc*256 + k0 + lhi*8);
                u32x4 wl = *(const u32x4*)(Wol + (size_t)oc*256 + k0 + lhi*8);
                acc4[j] = MFMA(oh, wh, acc4[j]);
                acc4[j] = MFMA(oh, wl, acc4[j]);
                acc4[j] = MFMA(ol, wh, acc4[j]);
            }
        }
        float msum = smsum;
        #pragma unroll
        for (int j = 0; j < 4; ++j) {
            float s = 0.f;
            #pragma unroll
            for (int r = 0; r < 4; ++r) s += msk[lhi*4 + r] * acc4[j][r];
            s += __shfl_xor(s, 16);
            s += __shfl_xor(s, 32);
            if (lhi == 0) {
                int col = w*64 + j*16 + l15;
                float val = (s + bo[col] * msum) / (msum + 1e-10f);
                if (out_f32) out_f32[(size_t)b*256 + col] = val;
                if (out_hi) {
                    U16 vH, vL; split_hl(val, vH, vL);
                    out_hi[(size_t)b*256 + col] = vH;
                    out_lo[(size_t)b*256 + col] = vL;
                }
            }
        }
    }
    if (t == 0 && outmask) outmask[b] = (smsum > 0.f) ? 1.f : 0.f;
}

extern "C" void kernel_launch(void* const* d_in, const int* in_sizes, int n_in,
                              void* d_out, int out_size, void* d_ws, size_t ws_size,
                              hipStream_t stream) {
    (void)in_sizes; (void)n_in; (void)out_size; (void)ws_size;
    const float* we  = (const float*)d_in[0];
    const int*   am  = (const int*)d_in[1];
    const float* wW  = (const float*)d_in[2];
    const float* wb  = (const float*)d_in[3];
    const float* wO  = (const float*)d_in[4];
    const float* wob = (const float*)d_in[5];
    const float* sW  = (const float*)d_in[6];
    const float* sb  = (const float*)d_in[7];
    const float* sO  = (const float*)d_in[8];
    const float* sob = (const float*)d_in[9];
    const float* cW  = (const float*)d_in[10];
    const float* cb  = (const float*)d_in[11];
    const float* cO  = (const float*)d_in[12];
    const float* cob = (const float*)d_in[13];

    U16* p = (U16*)d_ws;
    U16* sent_hi = p; p += 2048*256;
    U16* sent_lo = p; p += 2048*256;
    U16* sect_hi = p; p += 128*256;
    U16* sect_lo = p; p += 128*256;
    U16* w1qh = p; p += 768*256;  U16* w1ql = p; p += 768*256;
    U16* w1oh = p; p += 256*256;  U16* w1ol = p; p += 256*256;
    U16* w2qh = p; p += 768*256;  U16* w2ql = p; p += 768*256;
    U16* w2oh = p; p += 256*256;  U16* w2ol = p; p += 256*256;
    U16* w3qh = p; p += 768*256;  U16* w3ql = p; p += 768*256;
    U16* w3oh = p; p += 256*256;  U16* w3ol = p; p += 256*256;
    float* smaskb = (float*)p;
    float* cmaskb = smaskb + 2048;

    convert_w<<<768, 256, 0, stream>>>(wW, wO, w1qh, w1ql, w1oh, w1ol);
    convert_w<<<768, 256, 0, stream>>>(sW, sO, w2qh, w2ql, w2oh, w2ol);
    convert_w<<<768, 256, 0, stream>>>(cW, cO, w3qh, w3ql, w3oh, w3ol);
    word_mfma<<<2048, 256, 0, stream>>>(we, am, w1qh, w1ql, wb, w1oh, w1ol, wob,
                                        sent_hi, sent_lo, smaskb);
    mha_small<16><<<128, 256, 0, stream>>>(sent_hi, sent_lo, smaskb,
                                           w2qh, w2ql, sb, w2oh, w2ol, sob,
                                           nullptr, sect_hi, sect_lo, cmaskb);
    mha_small<8><<<16, 256, 0, stream>>>(sect_hi, sect_lo, cmaskb,
                                         w3qh, w3ql, cb, w3oh, w3ol, cob,
                                         (float*)d_out, nullptr, nullptr, nullptr);
}

// Round 9
// 520.436 us; speedup vs baseline: 9.3159x; 1.7651x over previous
//
#include <hip/hip_runtime.h>
#include <hip/hip_bf16.h>

// Hierarchical attention, 3 levels. Split-bf16 (hi/lo) MFMA for QKV/scores/PV;
// out-proj COMMUTED with the masked mean pool (both linear):
//   pooled_out = (masked_rowsum(O)) @ Wo^T + bo * msum, all in exact fp32.
// This removes the out-proj GEMM + its 64-AGPR accumulator (r8's spill source).
// LDS tiles: packed u32 (hi<<16|lo), 256B rows, XOR-16 swizzle (0-conflict).

typedef short bf16x8 __attribute__((ext_vector_type(8)));
typedef float f32x4 __attribute__((ext_vector_type(4)));
typedef unsigned int u32x4 __attribute__((ext_vector_type(4)));
typedef unsigned short U16;
typedef unsigned int U32;

__device__ __forceinline__ U32 bf16_rne(float f) {
    U32 u = __builtin_bit_cast(U32, f);
    return (u + 0x7FFFu + ((u >> 16) & 1u)) >> 16;
}
__device__ __forceinline__ void split_hl(float f, U16& h, U16& l) {
    U32 hu = bf16_rne(f);
    float hf = __builtin_bit_cast(float, hu << 16);
    h = (U16)hu;
    l = (U16)bf16_rne(f - hf);
}
__device__ __forceinline__ U32 pack_hl(float f) {
    U32 hu = bf16_rne(f);
    float hf = __builtin_bit_cast(float, hu << 16);
    U32 lo = bf16_rne(f - hf);
    return (hu << 16) | (lo & 0xFFFFu);
}

__device__ __forceinline__ void unpack8(u32x4 a, u32x4 b, u32x4& hi, u32x4& lo) {
    hi[0] = __builtin_amdgcn_perm(a[1], a[0], 0x07060302u);
    hi[1] = __builtin_amdgcn_perm(a[3], a[2], 0x07060302u);
    hi[2] = __builtin_amdgcn_perm(b[1], b[0], 0x07060302u);
    hi[3] = __builtin_amdgcn_perm(b[3], b[2], 0x07060302u);
    lo[0] = __builtin_amdgcn_perm(a[1], a[0], 0x05040100u);
    lo[1] = __builtin_amdgcn_perm(a[3], a[2], 0x05040100u);
    lo[2] = __builtin_amdgcn_perm(b[1], b[0], 0x05040100u);
    lo[3] = __builtin_amdgcn_perm(b[3], b[2], 0x05040100u);
}

#define MFMA(A, B, C) __builtin_amdgcn_mfma_f32_16x16x32_bf16( \
    __builtin_bit_cast(bf16x8, A), __builtin_bit_cast(bf16x8, B), C, 0, 0, 0)

// Packed-u32 tile (row stride 64 u32 = 256 B, 16 slots of 16B, XOR-16 swizzle).
__device__ __forceinline__ void tile_frag(const U32* tile, int row, int s0,
                                          u32x4& hi, u32x4& lo) {
    int m = row & 15;
    u32x4 a = *(const u32x4*)(tile + row * 64 + ((s0    ) ^ m) * 4);
    u32x4 b = *(const u32x4*)(tile + row * 64 + ((s0 + 1) ^ m) * 4);
    unpack8(a, b, hi, lo);
}
__device__ __forceinline__ void tile_put(U32* tile, int row, int col, float v) {
    tile[row * 64 + (((col >> 2) ^ (row & 15))) * 4 + (col & 3)] = pack_hl(v);
}

// ---- hi/lo plane helpers for mha_small ----
template <int RS, int SW>
__device__ __forceinline__ u32x4 fragp(const U16* base, int row, int k, int lhi) {
    int slot = ((k >> 3) + lhi) ^ (row & SW);
    return *(const u32x4*)(base + row * RS + slot * 8);
}
template <int RS, int SW>
__device__ __forceinline__ void put16(U16* base, int row, int col, U16 v) {
    int slot = (col >> 3) ^ (row & SW);
    base[row * RS + slot * 8 + (col & 7)] = v;
}
template <int RS, int SW>
__device__ __forceinline__ void put64(U16* base, int row, int col0,
                                      U16 v0, U16 v1, U16 v2, U16 v3) {
    int slot = (col0 >> 3) ^ (row & SW);
    U32* p = (U32*)(base + row * RS + slot * 8 + (col0 & 7));
    p[0] = (U32)v0 | ((U32)v1 << 16);
    p[1] = (U32)v2 | ((U32)v3 << 16);
}

__global__ __launch_bounds__(256) void convert_w(
    const float* __restrict__ Wq, const float* __restrict__ Wo,
    U16* __restrict__ qh, U16* __restrict__ ql,
    U16* __restrict__ oh, U16* __restrict__ ol)
{
    int i = blockIdx.x * 256 + threadIdx.x;
    if (i < 768 * 256) { U16 h, l; split_hl(Wq[i], h, l); qh[i] = h; ql[i] = l; }
    if (i < 256 * 256) { U16 h, l; split_hl(Wo[i], h, l); oh[i] = h; ol[i] = l; }
}

// ---- word level: 1 block = 1 sequence (L=64), 256 threads = 4 waves ----
__global__ __launch_bounds__(256, 2) void word_mfma(
    const float* __restrict__ x, const int* __restrict__ am,
    const U16* __restrict__ Wqh, const U16* __restrict__ Wql,
    const float* __restrict__ bqkv,
    const float* __restrict__ Wo32,   // fp32 [256][256]
    const float* __restrict__ bo,
    U16* __restrict__ sent_hi, U16* __restrict__ sent_lo,
    float* __restrict__ smask)
{
    __shared__ __align__(16) U32 xc[64 * 64];   // x chunk (swizzled)
    __shared__ __align__(16) U32 Qs[64 * 64];   // Q, later P
    __shared__ __align__(16) U32 Ks[64 * 64];   // K
    __shared__ __align__(16) U32 Vt[64 * 64];   // V^T [d][m]
    __shared__ float part[4][256];              // per-wave pooled-O partials
    __shared__ float opool[256];
    __shared__ float msk[64];
    __shared__ float smsum;

    const int t = threadIdx.x;
    const int w = t >> 6, l = t & 63, l15 = l & 15, lhi = l >> 4;
    const int b = blockIdx.x;
    const float* xb = x + (size_t)b * 16384;

    if (t < 64) msk[t] = (float)am[b * 64 + t];

    const int r0 = t >> 3, c8 = t & 7;
    const int r1 = r0 + 32;

    for (int h = 0; h < 4; ++h) {
        // ---------------- QKV over 4 k-chunks of 64 ----------------
        float4 s00 = *(const float4*)(xb + r0 * 256 + c8 * 8);
        float4 s01 = *(const float4*)(xb + r0 * 256 + c8 * 8 + 4);
        float4 s10 = *(const float4*)(xb + r1 * 256 + c8 * 8);
        float4 s11 = *(const float4*)(xb + r1 * 256 + c8 * 8 + 4);
        f32x4 acc[3][4];
        #pragma unroll
        for (int j = 0; j < 3; ++j)
            #pragma unroll
            for (int mt = 0; mt < 4; ++mt) acc[j][mt] = f32x4{0.f, 0.f, 0.f, 0.f};

        for (int kc = 0; kc < 4; ++kc) {
            __syncthreads();                    // xc writable
            {
                u32x4 p0, p1;
                p0[0] = pack_hl(s00.x); p0[1] = pack_hl(s00.y);
                p0[2] = pack_hl(s00.z); p0[3] = pack_hl(s00.w);
                p1[0] = pack_hl(s01.x); p1[1] = pack_hl(s01.y);
                p1[2] = pack_hl(s01.z); p1[3] = pack_hl(s01.w);
                int mm = r0 & 15;
                *(u32x4*)(xc + r0 * 64 + ((c8 * 2    ) ^ mm) * 4) = p0;
                *(u32x4*)(xc + r0 * 64 + ((c8 * 2 + 1) ^ mm) * 4) = p1;
                p0[0] = pack_hl(s10.x); p0[1] = pack_hl(s10.y);
                p0[2] = pack_hl(s10.z); p0[3] = pack_hl(s10.w);
                p1[0] = pack_hl(s11.x); p1[1] = pack_hl(s11.y);
                p1[2] = pack_hl(s11.z); p1[3] = pack_hl(s11.w);
                mm = r1 & 15;
                *(u32x4*)(xc + r1 * 64 + ((c8 * 2    ) ^ mm) * 4) = p0;
                *(u32x4*)(xc + r1 * 64 + ((c8 * 2 + 1) ^ mm) * 4) = p1;
            }
            __syncthreads();                    // xc readable
            if (kc < 3) {                       // prefetch next chunk (T14)
                s00 = *(const float4*)(xb + r0 * 256 + (kc + 1) * 64 + c8 * 8);
                s01 = *(const float4*)(xb + r0 * 256 + (kc + 1) * 64 + c8 * 8 + 4);
                s10 = *(const float4*)(xb + r1 * 256 + (kc + 1) * 64 + c8 * 8);
                s11 = *(const float4*)(xb + r1 * 256 + (kc + 1) * 64 + c8 * 8 + 4);
            }
            #pragma unroll
            for (int ks = 0; ks < 2; ++ks) {
                const int s0 = ks * 8 + lhi * 2;
                u32x4 xh[4], xl[4];
                #pragma unroll
                for (int mt = 0; mt < 4; ++mt)
                    tile_frag(xc, mt * 16 + l15, s0, xh[mt], xl[mt]);
                const int kk = kc * 64 + ks * 32 + lhi * 8;
                #pragma unroll
                for (int j = 0; j < 3; ++j) {
                    const size_t wr =
                        (size_t)(j * 256 + h * 64 + w * 16 + l15) * 256 + kk;
                    u32x4 wh = *(const u32x4*)(Wqh + wr);
                    u32x4 wl = *(const u32x4*)(Wql + wr);
                    #pragma unroll
                    for (int mt = 0; mt < 4; ++mt) {
                        acc[j][mt] = MFMA(xh[mt], wh, acc[j][mt]);
                        acc[j][mt] = MFMA(xh[mt], wl, acc[j][mt]);
                        acc[j][mt] = MFMA(xl[mt], wh, acc[j][mt]);
                    }
                }
            }
        }
        // ---------------- write Q / K / Vt tiles ----------------
        {
            const float bQ = bqkv[      h * 64 + w * 16 + l15];
            const float bK = bqkv[256 + h * 64 + w * 16 + l15];
            const float bV = bqkv[512 + h * 64 + w * 16 + l15];
            #pragma unroll
            for (int mt = 0; mt < 4; ++mt) {
                #pragma unroll
                for (int r = 0; r < 4; ++r) {
                    tile_put(Qs, mt * 16 + lhi * 4 + r, w * 16 + l15, acc[0][mt][r] + bQ);
                    tile_put(Ks, mt * 16 + lhi * 4 + r, w * 16 + l15, acc[1][mt][r] + bK);
                }
                const int d = w * 16 + l15;
                u32x4 pv;
                #pragma unroll
                for (int r = 0; r < 4; ++r) pv[r] = pack_hl(acc[2][mt][r] + bV);
                const int cs = (mt * 4 + lhi) ^ (d & 15);
                *(u32x4*)(Vt + d * 64 + cs * 4) = pv;
            }
        }
        __syncthreads();   // tiles ready for all waves
        if (h == 0 && t == 0) {
            float s = 0.f;
            for (int i = 0; i < 64; ++i) s += msk[i];
            smsum = s;
        }

        // ------- scores + softmax + P (wave w owns row-tile w) -------
        {
            f32x4 sa[4];
            #pragma unroll
            for (int i = 0; i < 4; ++i) sa[i] = f32x4{0.f, 0.f, 0.f, 0.f};
            #pragma unroll
            for (int ks = 0; ks < 2; ++ks) {
                const int s0 = ks * 8 + lhi * 2;
                u32x4 qh, ql;
                tile_frag(Qs, w * 16 + l15, s0, qh, ql);
                #pragma unroll
                for (int nt = 0; nt < 4; ++nt) {
                    u32x4 kh, kl;
                    tile_frag(Ks, nt * 16 + l15, s0, kh, kl);
                    sa[nt] = MFMA(qh, kh, sa[nt]);
                    sa[nt] = MFMA(qh, kl, sa[nt]);
                    sa[nt] = MFMA(ql, kh, sa[nt]);
                }
            }
            float sc[4][4];
            #pragma unroll
            for (int nt = 0; nt < 4; ++nt) {
                const float mterm = (1.0f - msk[nt * 16 + l15]) * -1e9f;
                #pragma unroll
                for (int r = 0; r < 4; ++r) sc[nt][r] = sa[nt][r] * 0.125f + mterm;
            }
            #pragma unroll
            for (int r = 0; r < 4; ++r) {
                float m = fmaxf(fmaxf(sc[0][r], sc[1][r]), fmaxf(sc[2][r], sc[3][r]));
                #pragma unroll
                for (int off = 1; off < 16; off <<= 1) m = fmaxf(m, __shfl_xor(m, off));
                float e0 = expf(sc[0][r] - m), e1 = expf(sc[1][r] - m);
                float e2 = expf(sc[2][r] - m), e3 = expf(sc[3][r] - m);
                float s = e0 + e1 + e2 + e3;
                #pragma unroll
                for (int off = 1; off < 16; off <<= 1) s += __shfl_xor(s, off);
                const float inv = 1.0f / s;
                sc[0][r] = e0 * inv; sc[1][r] = e1 * inv;
                sc[2][r] = e2 * inv; sc[3][r] = e3 * inv;
            }
            #pragma unroll
            for (int nt = 0; nt < 4; ++nt)
                #pragma unroll
                for (int r = 0; r < 4; ++r)
                    tile_put(Qs, w * 16 + lhi * 4 + r, nt * 16 + l15, sc[nt][r]);
        }
        // ------- PV (no barrier: P own rows, Vt barriered) -------
        {
            f32x4 pa[4];
            #pragma unroll
            for (int i = 0; i < 4; ++i) pa[i] = f32x4{0.f, 0.f, 0.f, 0.f};
            #pragma unroll
            for (int ks = 0; ks < 2; ++ks) {
                const int s0 = ks * 8 + lhi * 2;
                u32x4 ph, pl;
                tile_frag(Qs, w * 16 + l15, s0, ph, pl);
                #pragma unroll
                for (int nt = 0; nt < 4; ++nt) {
                    u32x4 vh, vl;
                    tile_frag(Vt, nt * 16 + l15, s0, vh, vl);
                    pa[nt] = MFMA(ph, vh, pa[nt]);
                    pa[nt] = MFMA(ph, vl, pa[nt]);
                    pa[nt] = MFMA(pl, vh, pa[nt]);
                }
            }
            // ---- masked row-sum of O_h (pool BEFORE out-proj; they commute) ----
            #pragma unroll
            for (int nt = 0; nt < 4; ++nt) {
                float s = 0.f;
                #pragma unroll
                for (int r = 0; r < 4; ++r)
                    s += msk[w * 16 + lhi * 4 + r] * pa[nt][r];
                s += __shfl_xor(s, 16);
                s += __shfl_xor(s, 32);
                if (lhi == 0) part[w][h * 64 + nt * 16 + l15] = s;  // own slot
            }
        }
        // next head's kc-loop barrier orders xc/Qs/Ks/Vt rewrites after reads
    }

    __syncthreads();   // all part writes done
    opool[t] = part[0][t] + part[1][t] + part[2][t] + part[3][t];
    __syncthreads();
    {
        // out[j] = (opool . Wo[j,:] + bo[j]*msum) / (msum + eps), exact fp32
        const float* wrow = Wo32 + (size_t)t * 256;
        float s = 0.f;
        #pragma unroll 8
        for (int c = 0; c < 256; c += 4) {
            float4 wv = *(const float4*)(wrow + c);
            s += opool[c] * wv.x + opool[c + 1] * wv.y
               + opool[c + 2] * wv.z + opool[c + 3] * wv.w;
        }
        float m = smsum;
        float val = (s + bo[t] * m) / (m + 1e-10f);
        U16 vH, vL; split_hl(val, vH, vL);
        sent_hi[(size_t)b * 256 + t] = vH;
        sent_lo[(size_t)b * 256 + t] = vL;
    }
    if (t == 0) smask[b] = (smsum > 0.f) ? 1.f : 0.f;
}

// ---- levels 2/3: L in {16, 8}; unchanged from r8 (passes, ~30 us total) ----
template <int L>
__global__ __launch_bounds__(256) void mha_small(
    const U16* __restrict__ xh, const U16* __restrict__ xl,
    const float* __restrict__ mk,
    const U16* __restrict__ Wqh, const U16* __restrict__ Wql,
    const float* __restrict__ bqkv,
    const U16* __restrict__ Woh, const U16* __restrict__ Wol,
    const float* __restrict__ bo,
    float* __restrict__ out_f32, U16* __restrict__ out_hi, U16* __restrict__ out_lo,
    float* __restrict__ outmask)
{
    __shared__ __align__(16) U16 xs_h[16*256], xs_l[16*256];
    __shared__ __align__(16) U16 Qh_[16*256], Ql_[16*256];
    __shared__ __align__(16) U16 Kh_[16*256], Kl_[16*256];
    __shared__ __align__(16) U16 Vh_[256*32], Vl_[256*32];
    __shared__ __align__(16) U16 Ph_[4][16*32], Pl_[4][16*32];
    __shared__ __align__(16) U16 Oh_[16*256], Ol_[16*256];
    __shared__ float msk[16];
    __shared__ float smsum;

    const int t = threadIdx.x;
    const int w = t >> 6, l = t & 63, l15 = l & 15, lhi = l >> 4;
    const int b = blockIdx.x;

    if (t < 16) msk[t] = (t < L) ? mk[b*L + t] : 0.f;

    #pragma unroll
    for (int i = 0; i < 2; ++i) {
        int c = i*256 + t;
        int row = c >> 5, c8 = c & 31;
        u32x4 hv = u32x4{0,0,0,0}, lv = u32x4{0,0,0,0};
        if (row < L) {
            hv = *(const u32x4*)(xh + ((size_t)b*L + row)*256 + c8*8);
            lv = *(const u32x4*)(xl + ((size_t)b*L + row)*256 + c8*8);
        }
        int slot = c8 ^ (row & 7);
        *(u32x4*)(xs_h + row*256 + slot*8) = hv;
        *(u32x4*)(xs_l + row*256 + slot*8) = lv;
    }
    #pragma unroll
    for (int i = 0; i < 4; ++i) {
        int c = i*256 + t;
        *(u32x4*)(Vh_ + c*8) = u32x4{0,0,0,0};
        *(u32x4*)(Vl_ + c*8) = u32x4{0,0,0,0};
    }
    *(u32x4*)(&Ph_[0][0] + t*8) = u32x4{0,0,0,0};
    *(u32x4*)(&Pl_[0][0] + t*8) = u32x4{0,0,0,0};
    __syncthreads();
    if (t == 0) { float s = 0.f; for (int i = 0; i < 16; ++i) s += msk[i]; smsum = s; }

    {
        f32x4 acc[12];
        #pragma unroll
        for (int i = 0; i < 12; ++i) acc[i] = f32x4{0.f,0.f,0.f,0.f};
        #pragma unroll 2
        for (int k0 = 0; k0 < 256; k0 += 32) {
            u32x4 ah = fragp<256,7>(xs_h, l15, k0, lhi);
            u32x4 al = fragp<256,7>(xs_l, l15, k0, lhi);
            #pragma unroll
            for (int j = 0; j < 12; ++j) {
                int u = w*12 + j;
                u32x4 wh = *(const u32x4*)(Wqh + (size_t)(u*16 + l15)*256 + k0 + lhi*8);
                u32x4 wl = *(const u32x4*)(Wql + (size_t)(u*16 + l15)*256 + k0 + lhi*8);
                acc[j] = MFMA(ah, wh, acc[j]);
                acc[j] = MFMA(ah, wl, acc[j]);
                acc[j] = MFMA(al, wh, acc[j]);
            }
        }
        #pragma unroll
        for (int j = 0; j < 12; ++j) {
            int u = w*12 + j;
            int mat = u >> 4, cg = u & 15;
            float bias = bqkv[u*16 + l15];
            if (mat < 2) {
                U16* dh = (mat == 0) ? Qh_ : Kh_;
                U16* dl = (mat == 0) ? Ql_ : Kl_;
                #pragma unroll
                for (int r = 0; r < 4; ++r) {
                    U16 vH, vL; split_hl(acc[j][r] + bias, vH, vL);
                    put16<256,7>(dh, lhi*4 + r, cg*16 + l15, vH);
                    put16<256,7>(dl, lhi*4 + r, cg*16 + l15, vL);
                }
            } else {
                U16 h4[4], l4[4];
                #pragma unroll
                for (int r = 0; r < 4; ++r) split_hl(acc[j][r] + bias, h4[r], l4[r]);
                put64<32,3>(Vh_, cg*16 + l15, lhi*4, h4[0],h4[1],h4[2],h4[3]);
                put64<32,3>(Vl_, cg*16 + l15, lhi*4, l4[0],l4[1],l4[2],l4[3]);
            }
        }
    }
    __syncthreads();

    {
        const int h = w;
        f32x4 sa = f32x4{0.f,0.f,0.f,0.f};
        #pragma unroll
        for (int k0 = 0; k0 < 64; k0 += 32) {
            u32x4 qh = fragp<256,7>(Qh_, l15, h*64 + k0, lhi);
            u32x4 ql = fragp<256,7>(Ql_, l15, h*64 + k0, lhi);
            u32x4 kh = fragp<256,7>(Kh_, l15, h*64 + k0, lhi);
            u32x4 kl = fragp<256,7>(Kl_, l15, h*64 + k0, lhi);
            sa = MFMA(qh, kh, sa);
            sa = MFMA(qh, kl, sa);
            sa = MFMA(ql, kh, sa);
        }
        float sc[4];
        float mterm = (1.0f - msk[l15]) * -1e9f;
        #pragma unroll
        for (int r = 0; r < 4; ++r) sc[r] = sa[r] * 0.125f + mterm;
        #pragma unroll
        for (int r = 0; r < 4; ++r) {
            float m = sc[r];
            #pragma unroll
            for (int off = 1; off < 16; off <<= 1) m = fmaxf(m, __shfl_xor(m, off));
            float e = expf(sc[r] - m);
            float s = e;
            #pragma unroll
            for (int off = 1; off < 16; off <<= 1) s += __shfl_xor(s, off);
            sc[r] = e / s;
        }
        #pragma unroll
        for (int r = 0; r < 4; ++r) {
            U16 vH, vL; split_hl(sc[r], vH, vL);
            put16<32,3>(&Ph_[h][0], lhi*4 + r, l15, vH);
            put16<32,3>(&Pl_[h][0], lhi*4 + r, l15, vL);
        }
        f32x4 pa[4];
        #pragma unroll
        for (int i = 0; i < 4; ++i) pa[i] = f32x4{0.f,0.f,0.f,0.f};
        {
            u32x4 ph = fragp<32,3>(&Ph_[h][0], l15, 0, lhi);
            u32x4 pl = fragp<32,3>(&Pl_[h][0], l15, 0, lhi);
            #pragma unroll
            for (int ntl = 0; ntl < 4; ++ntl) {
                u32x4 vh = fragp<32,3>(Vh_, h*64 + ntl*16 + l15, 0, lhi);
                u32x4 vl = fragp<32,3>(Vl_, h*64 + ntl*16 + l15, 0, lhi);
                pa[ntl] = MFMA(ph, vh, pa[ntl]);
                pa[ntl] = MFMA(ph, vl, pa[ntl]);
                pa[ntl] = MFMA(pl, vh, pa[ntl]);
            }
        }
        #pragma unroll
        for (int ntl = 0; ntl < 4; ++ntl) {
            #pragma unroll
            for (int r = 0; r < 4; ++r) {
                U16 vH, vL; split_hl(pa[ntl][r], vH, vL);
                put16<256,7>(Oh_, lhi*4 + r, h*64 + ntl*16 + l15, vH);
                put16<256,7>(Ol_, lhi*4 + r, h*64 + ntl*16 + l15, vL);
            }
        }
    }
    __syncthreads();

    {
        f32x4 acc4[4];
        #pragma unroll
        for (int i = 0; i < 4; ++i) acc4[i] = f32x4{0.f,0.f,0.f,0.f};
        #pragma unroll 2
        for (int k0 = 0; k0 < 256; k0 += 32) {
            u32x4 oh = fragp<256,7>(Oh_, l15, k0, lhi);
            u32x4 ol = fragp<256,7>(Ol_, l15, k0, lhi);
            #pragma unroll
            for (int j = 0; j < 4; ++j) {
                int oc = w*64 + j*16 + l15;
                u32x4 wh = *(const u32x4*)(Woh + (size_t)oc*256 + k0 + lhi*8);
                u32x4 wl = *(const u32x4*)(Wol + (size_t)oc*256 + k0 + lhi*8);
                acc4[j] = MFMA(oh, wh, acc4[j]);
                acc4[j] = MFMA(oh, wl, acc4[j]);
                acc4[j] = MFMA(ol, wh, acc4[j]);
            }
        }
        float msum = smsum;
        #pragma unroll
        for (int j = 0; j < 4; ++j) {
            float s = 0.f;
            #pragma unroll
            for (int r = 0; r < 4; ++r) s += msk[lhi*4 + r] * acc4[j][r];
            s += __shfl_xor(s, 16);
            s += __shfl_xor(s, 32);
            if (lhi == 0) {
                int col = w*64 + j*16 + l15;
                float val = (s + bo[col] * msum) / (msum + 1e-10f);
                if (out_f32) out_f32[(size_t)b*256 + col] = val;
                if (out_hi) {
                    U16 vH, vL; split_hl(val, vH, vL);
                    out_hi[(size_t)b*256 + col] = vH;
                    out_lo[(size_t)b*256 + col] = vL;
                }
            }
        }
    }
    if (t == 0 && outmask) outmask[b] = (smsum > 0.f) ? 1.f : 0.f;
}

extern "C" void kernel_launch(void* const* d_in, const int* in_sizes, int n_in,
                              void* d_out, int out_size, void* d_ws, size_t ws_size,
                              hipStream_t stream) {
    (void)in_sizes; (void)n_in; (void)out_size; (void)ws_size;
    const float* we  = (const float*)d_in[0];
    const int*   am  = (const int*)d_in[1];
    const float* wW  = (const float*)d_in[2];
    const float* wb  = (const float*)d_in[3];
    const float* wO  = (const float*)d_in[4];
    const float* wob = (const float*)d_in[5];
    const float* sW  = (const float*)d_in[6];
    const float* sb  = (const float*)d_in[7];
    const float* sO  = (const float*)d_in[8];
    const float* sob = (const float*)d_in[9];
    const float* cW  = (const float*)d_in[10];
    const float* cb  = (const float*)d_in[11];
    const float* cO  = (const float*)d_in[12];
    const float* cob = (const float*)d_in[13];

    U16* p = (U16*)d_ws;
    U16* sent_hi = p; p += 2048*256;
    U16* sent_lo = p; p += 2048*256;
    U16* sect_hi = p; p += 128*256;
    U16* sect_lo = p; p += 128*256;
    U16* w1qh = p; p += 768*256;  U16* w1ql = p; p += 768*256;
    U16* w1oh = p; p += 256*256;  U16* w1ol = p; p += 256*256;
    U16* w2qh = p; p += 768*256;  U16* w2ql = p; p += 768*256;
    U16* w2oh = p; p += 256*256;  U16* w2ol = p; p += 256*256;
    U16* w3qh = p; p += 768*256;  U16* w3ql = p; p += 768*256;
    U16* w3oh = p; p += 256*256;  U16* w3ol = p; p += 256*256;
    float* smaskb = (float*)p;
    float* cmaskb = smaskb + 2048;

    convert_w<<<768, 256, 0, stream>>>(wW, wO, w1qh, w1ql, w1oh, w1ol);
    convert_w<<<768, 256, 0, stream>>>(sW, sO, w2qh, w2ql, w2oh, w2ol);
    convert_w<<<768, 256, 0, stream>>>(cW, cO, w3qh, w3ql, w3oh, w3ol);
    word_mfma<<<2048, 256, 0, stream>>>(we, am, w1qh, w1ql, wb, wO, wob,
                                        sent_hi, sent_lo, smaskb);
    mha_small<16><<<128, 256, 0, stream>>>(sent_hi, sent_lo, smaskb,
                                           w2qh, w2ql, sb, w2oh, w2ol, sob,
                                           nullptr, sect_hi, sect_lo, cmaskb);
    mha_small<8><<<16, 256, 0, stream>>>(sect_hi, sect_lo, cmaskb,
                                         w3qh, w3ql, cb, w3oh, w3ol, cob,
                                         (float*)d_out, nullptr, nullptr, nullptr);
}